// Round 9
// baseline (817.290 us; speedup 1.0000x reference)
//
#include <hip/hip_runtime.h>
#include <hip/hip_bf16.h>

#define NE 16
#define NN 4
#define DDIM 128
#define KD 64
#define HD 45
#define E_TOT 304

typedef _Float16 half8 __attribute__((ext_vector_type(8)));
typedef float floatx4 __attribute__((ext_vector_type(4)));

// ws byte offsets (static region)
#define OFF_FLAG_B 0
#define OFF_B1_B   64       // fp32 [9][48] (pad cols 45..47 = 0)
#define OFF_XT_B   1792     // fp32 [128]
#define OFF_H0_B   2304     // f16 [2][64]
#define OFF_YW_B   2560     // f16 [4][64]
#define OFF_W1_B   3072     // f16 frag [9][3nt][512]
#define OFF_W2_B   30720    // f16 frag [9][4nt][2kt][512] (rows 45..63 zero)
#define OFF_GW_B   104448   // f16 frag [9][8nt][2kt][512]
#define OFF_HW_B   251904   // f16 frag [4][4nt][4kt][512]
#define OFF_DYN_B  317440   // dynamic per-B buffers follow

__device__ __forceinline__ float ldf(const void* p, long i, int f32) {
    if (f32) return ((const float*)p)[i];
    unsigned int u = ((unsigned int)((const unsigned short*)p)[i]) << 16;
    return __uint_as_float(u);
}

__global__ void detect_kernel(const unsigned short* rs16, char* wsB) {
    __shared__ int bad;
    if (threadIdx.x == 0) bad = 0;
    __syncthreads();
    for (int i = threadIdx.x; i < 2048; i += 256) {
        unsigned int u = ((unsigned int)rs16[i]) << 16;
        float v = __uint_as_float(u);
        if (!(fabsf(v) < 1e6f)) atomicOr(&bad, 1);
    }
    __syncthreads();
    if (threadIdx.x == 0) *(int*)(wsB + OFF_FLAG_B) = bad ? 1 : 0;
}

__global__ void prep_kernel(const void* w1, const void* b1, const void* w2, const void* h0,
                            const void* hW, const void* gW, const void* Yw, const void* Xt,
                            char* wsB) {
    const int f32 = *(const int*)(wsB + OFF_FLAG_B);
    int i = blockIdx.x * 256 + threadIdx.x;
    _Float16* W1F = (_Float16*)(wsB + OFF_W1_B);
    _Float16* W2F = (_Float16*)(wsB + OFF_W2_B);
    _Float16* GWF = (_Float16*)(wsB + OFF_GW_B);
    _Float16* HWF = (_Float16*)(wsB + OFF_HW_B);
    float*    B1  = (float*)(wsB + OFF_B1_B);
    float*    XT  = (float*)(wsB + OFF_XT_B);
    _Float16* H0F = (_Float16*)(wsB + OFF_H0_B);
    _Float16* YWF = (_Float16*)(wsB + OFF_YW_B);

    if (i < 13824) {  // W1 frags
        int lj = i / 1536, rem = i % 1536;
        int nt = rem >> 9, lane = (rem & 511) >> 3, e = rem & 7;
        int row = ((lane >> 4) << 3) + e;
        int col = (nt << 4) + (lane & 15);
        W1F[i] = (_Float16)((col < 45) ? ldf(w1, lj * 1440 + row * 45 + col, f32) : 0.f);
    }
    if (i < 36864) {  // W2 frags (rows >= 45 zero)
        int lj = i / 4096, rem = i & 4095;
        int nt = rem >> 10, kt = (rem >> 9) & 1, lane = (rem & 511) >> 3, e = rem & 7;
        int row = (kt << 5) + ((lane >> 4) << 3) + e;
        int col = (nt << 4) + (lane & 15);
        W2F[i] = (_Float16)((row < 45) ? ldf(w2, lj * 2880 + row * 64 + col, f32) : 0.f);
    }
    if (i < 73728) {  // gW frags
        int lj = i >> 13, rem = i & 8191;
        int nt = rem >> 10, kt = (rem >> 9) & 1, lane = (rem & 511) >> 3, e = rem & 7;
        int row = (kt << 5) + ((lane >> 4) << 3) + e;
        int col = (nt << 4) + (lane & 15);
        GWF[i] = (_Float16)ldf(gW, lj * 8192 + row * 128 + col, f32);
    }
    if (i < 32768) {  // hW frags
        int lj = i >> 13, rem = i & 8191;
        int nt = rem >> 11, kt = (rem >> 9) & 3, lane = (rem & 511) >> 3, e = rem & 7;
        int row = (kt << 5) + ((lane >> 4) << 3) + e;
        int col = (nt << 4) + (lane & 15);
        HWF[i] = (_Float16)ldf(hW, lj * 8192 + row * 64 + col, f32);
    }
    if (i < 432) { int lj = i / 48, n = i % 48; B1[i] = (n < 45) ? ldf(b1, lj * 45 + n, f32) : 0.f; }
    if (i < 128) XT[i] = ldf(Xt, i, f32);
    if (i < 128) H0F[i] = (_Float16)ldf(h0, i, f32);
    if (i < 256) YWF[i] = (_Float16)ldf(Yw, i, f32);
}

__global__ void dist_kernel(const void* __restrict__ rs, const void* __restrict__ coords,
                            const int* __restrict__ same_s, const int* __restrict__ same_r,
                            const int* __restrict__ anti_s, const int* __restrict__ anti_r,
                            const int* __restrict__ ne_s,   const int* __restrict__ ne_r,
                            const char* __restrict__ wsB, float* __restrict__ dLG, int Bn) {
    const int f32 = *(const int*)(wsB + OFF_FLAG_B);
    int idx = blockIdx.x * 256 + threadIdx.x;
    if (idx >= Bn * 304) return;
    int b = idx / 304, e = idx - b * 304;
    int s, r;
    if (e < 112)      { s = same_s[e];       r = same_r[e]; }
    else if (e < 240) { s = anti_s[e - 112]; r = anti_r[e - 112]; }
    else              { s = ne_s[e - 240];   r = ne_r[e - 240]; }
    long rb = ((long)b * NE + r) * 3;
    float bx = ldf(rs, rb + 0, f32), by = ldf(rs, rb + 1, f32), bz = ldf(rs, rb + 2, f32);
    float ax, ay, az;
    if (e < 240) {
        long sb = ((long)b * NE + s) * 3;
        ax = ldf(rs, sb + 0, f32); ay = ldf(rs, sb + 1, f32); az = ldf(rs, sb + 2, f32);
    } else {
        ax = ldf(coords, s * 3 + 0, f32); ay = ldf(coords, s * 3 + 1, f32); az = ldf(coords, s * 3 + 2, f32);
    }
    float dx = ax - bx, dy = ay - by, dz = az - bz;
    dLG[idx] = sqrtf(dx * dx + dy * dy + dz * dz);
}

__device__ __forceinline__ half8 mkfeat(float d, int qd) {
    float env = d * d * __expf(-d);
    half8 a;
    #pragma unroll
    for (int ii = 0; ii < 8; ++ii) {
        float qf = (float)(qd * 8 + ii) * (1.f / 31.f);
        float mu = 10.f * qf * qf;
        float isg = 7.f * __builtin_amdgcn_rcpf(1.f + 10.f * qf);
        float tt = (d - mu) * isg;
        a[ii] = (_Float16)(env * __expf(-tt * tt));
    }
    return a;
}

// ====== edge kernel: block = (j, b); 4 waves x <=2 tiles; LDS scatter -> zG ======
template<int L>
__global__ __launch_bounds__(256, 4)
void edge_kernel(const int* __restrict__ same_s, const int* __restrict__ same_r,
                 const int* __restrict__ anti_s, const int* __restrict__ anti_r,
                 const int* __restrict__ ne_s,   const int* __restrict__ ne_r,
                 const char* __restrict__ wsB, const float* __restrict__ dLG,
                 const _Float16* __restrict__ hxG, _Float16* __restrict__ zG) {
    const int j = blockIdx.x, b = blockIdx.y;
    const int tid = threadIdx.x;
    const int wv = tid >> 6, lane = tid & 63;
    const int qd = lane >> 4, lm = lane & 15;

    __shared__ float zbuf[16 * 68];                    // 4352 B
    __shared__ _Float16 hxS[16 * 72];                  // 2304 B
    __shared__ unsigned char esL[128], erL[128];
    __shared__ __align__(16) _Float16 hidA[4][1024];   // 8192 B

    const half8* W1F = (const half8*)(wsB + OFF_W1_B);
    const half8* W2F = (const half8*)(wsB + OFF_W2_B);
    const float* B1  = (const float*)(wsB + OFF_B1_B);
    const _Float16* H0F = (const _Float16*)(wsB + OFF_H0_B);
    const _Float16* YWF = (const _Float16*)(wsB + OFF_YW_B);

    const int lj = L * 3 + j;
    const int ecnt = (j == 0) ? 112 : ((j == 1) ? 128 : 64);
    const int t0   = (j == 0) ? 0 : ((j == 1) ? 7 : 15);
    const int tn   = (j == 0) ? 7 : ((j == 1) ? 8 : 4);
    const int* ss = (j == 0) ? same_s : ((j == 1) ? anti_s : ne_s);
    const int* rr = (j == 0) ? same_r : ((j == 1) ? anti_r : ne_r);

    // ---- stage: indices, hx slice, zero zbuf ----
    for (int i = tid; i < ecnt; i += 256) { esL[i] = (unsigned char)ss[i]; erL[i] = (unsigned char)rr[i]; }
    if (j < 2) {
        if (L == 0) {
            for (int i = tid; i < 1024; i += 256)
                hxS[(i >> 6) * 72 + (i & 63)] = H0F[j * 64 + (i & 63)];
        } else {
            for (int i = tid; i < 1024; i += 256)
                hxS[(i >> 6) * 72 + (i & 63)] = hxG[(size_t)b * 2048 + j * 1024 + i];
        }
    } else {
        for (int i = tid; i < 256; i += 256)
            hxS[(i >> 6) * 72 + (i & 63)] = YWF[i];
    }
    for (int i = tid; i < 16 * 68; i += 256) zbuf[i] = 0.f;
    {   // zero own-wave hid (cols 45..63 must stay finite zero)
        _Float16* hid = hidA[wv];
        half8 z8 = {0,0,0,0,0,0,0,0};
        *(half8*)(hid + lane * 8) = z8;
        *(half8*)(hid + 512 + lane * 8) = z8;
    }
    __syncthreads();

    // ---- weights in registers (once per block) ----
    const half8* W1F_lj = W1F + lj * 192;
    half8 w0 = W1F_lj[lane], w1v = W1F_lj[64 + lane], w2v = W1F_lj[128 + lane];
    float bi0 = B1[lj * 48 + lm], bi1 = B1[lj * 48 + 16 + lm], bi2 = B1[lj * 48 + 32 + lm];
    const half8* W2F_lj = W2F + lj * 512;
    half8 bk[4][2];
    #pragma unroll
    for (int nt = 0; nt < 4; ++nt) {
        bk[nt][0] = W2F_lj[nt * 128 + lane];
        bk[nt][1] = W2F_lj[nt * 128 + 64 + lane];
    }

    _Float16* hid = hidA[wv];
    for (int tt = wv; tt < tn; tt += 4) {
        const int t = t0 + tt;
        float d = dLG[(size_t)b * 304 + t * 16 + lm];
        half8 fa = mkfeat(d, qd);
        floatx4 c0 = {0.f,0.f,0.f,0.f}, c1 = c0, c2 = c0;
        c0 = __builtin_amdgcn_mfma_f32_16x16x32_f16(fa, w0,  c0, 0, 0, 0);
        c1 = __builtin_amdgcn_mfma_f32_16x16x32_f16(fa, w1v, c1, 0, 0, 0);
        c2 = __builtin_amdgcn_mfma_f32_16x16x32_f16(fa, w2v, c2, 0, 0, 0);
        #pragma unroll
        for (int r = 0; r < 4; ++r) {
            int row = qd * 4 + r;
            float v0 = c0[r] + bi0, v1 = c1[r] + bi1, v2 = c2[r] + bi2;
            v0 = v0 * __builtin_amdgcn_rcpf(1.f + __expf(-v0));
            v1 = v1 * __builtin_amdgcn_rcpf(1.f + __expf(-v1));
            v2 = v2 * __builtin_amdgcn_rcpf(1.f + __expf(-v2));
            hid[row * 64 + lm]      = (_Float16)v0;
            hid[row * 64 + 16 + lm] = (_Float16)v1;
            hid[row * 64 + 32 + lm] = (_Float16)v2;
        }
        half8 a0 = *(const half8*)(hid + lm * 64 + qd * 8);
        half8 a1 = *(const half8*)(hid + lm * 64 + 32 + qd * 8);
        #pragma unroll
        for (int nt = 0; nt < 4; ++nt) {
            floatx4 acc = {0.f,0.f,0.f,0.f};
            acc = __builtin_amdgcn_mfma_f32_16x16x32_f16(a0, bk[nt][0], acc, 0, 0, 0);
            acc = __builtin_amdgcn_mfma_f32_16x16x32_f16(a1, bk[nt][1], acc, 0, 0, 0);
            const int k = nt * 16 + lm;
            #pragma unroll
            for (int r = 0; r < 4; ++r) {
                int e = tt * 16 + qd * 4 + r;   // class-local edge index
                int s = esL[e], rcv = erL[e];
                float weh = acc[r] * (float)hxS[s * 72 + k];
                atomicAdd(&zbuf[rcv * 68 + k], weh);
            }
        }
    }
    __syncthreads();
    for (int i = tid; i < 1024; i += 256)
        zG[(size_t)b * 3072 + j * 1024 + i] = (_Float16)zbuf[(i >> 6) * 68 + (i & 63)];
}

// ====== tailhx kernel: block = b; tail (4 waves x 2 tiles) -> LDS -> hx (8 tasks) ======
template<int L, bool LAST>
__global__ __launch_bounds__(256, 4)
void tailhx_kernel(const char* __restrict__ wsB,
                   const _Float16* __restrict__ zG,
                   float* __restrict__ elecC, _Float16* __restrict__ hxG,
                   void* __restrict__ out) {
    const int b = blockIdx.x;
    const int q = threadIdx.x >> 6, lane = threadIdx.x & 63;
    const int qd = lane >> 4, lm = lane & 15;
    const int f32 = *(const int*)(wsB + OFF_FLAG_B);

    __shared__ __align__(16) _Float16 elecB[16 * 136];

    const half8* GWF = (const half8*)(wsB + OFF_GW_B);
    const half8* HWF = (const half8*)(wsB + OFF_HW_B);
    const float* XT  = (const float*)(wsB + OFF_XT_B);

    half8 zf[6];
    #pragma unroll
    for (int jj = 0; jj < 6; ++jj) {
        int j = jj >> 1, kh = jj & 1;
        zf[jj] = *(const half8*)(zG + (size_t)b * 3072 + j * 1024 + lm * 64 + kh * 32 + qd * 8);
    }
    #pragma unroll
    for (int u = 0; u < 2; ++u) {
        int t2 = q * 2 + u;
        floatx4 acc;
        if (L == 0) {
            float xv = XT[t2 * 16 + lm];
            acc[0] = xv; acc[1] = xv; acc[2] = xv; acc[3] = xv;
        } else {
            acc = *(const floatx4*)(elecC + (size_t)b * 2048 + (size_t)((qd * 8 + t2) * 16 + lm) * 4);
        }
        #pragma unroll
        for (int jj = 0; jj < 6; ++jj) {
            int j = jj >> 1, kh = jj & 1;
            half8 g = GWF[(L * 3 + j) * 1024 + t2 * 128 + kh * 64 + lane];
            acc = __builtin_amdgcn_mfma_f32_16x16x32_f16(zf[jj], g, acc, 0, 0, 0);
        }
        if (LAST) {
            if (f32) {
                float* o = (float*)out + (size_t)b * 2048;
                #pragma unroll
                for (int r = 0; r < 4; ++r) o[(qd * 4 + r) * 128 + t2 * 16 + lm] = acc[r];
            } else {
                __hip_bfloat16* o = (__hip_bfloat16*)out + (size_t)b * 2048;
                #pragma unroll
                for (int r = 0; r < 4; ++r) o[(qd * 4 + r) * 128 + t2 * 16 + lm] = __float2bfloat16(acc[r]);
            }
        } else {
            *(floatx4*)(elecC + (size_t)b * 2048 + (size_t)((qd * 8 + t2) * 16 + lm) * 4) = acc;
            #pragma unroll
            for (int r = 0; r < 4; ++r)
                elecB[(qd * 4 + r) * 136 + t2 * 16 + lm] = (_Float16)acc[r];
        }
    }
    if (!LAST) {
        __syncthreads();
        half8 ae[4];
        #pragma unroll
        for (int kt = 0; kt < 4; ++kt)
            ae[kt] = *(const half8*)(elecB + lm * 136 + kt * 32 + qd * 8);
        #pragma unroll
        for (int u = 0; u < 2; ++u) {
            int idx = q * 2 + u;
            int j = idx >> 2, nt = idx & 3;
            floatx4 acc = {0.f,0.f,0.f,0.f};
            #pragma unroll
            for (int kt = 0; kt < 4; ++kt) {
                half8 g = HWF[(size_t)(((L * 2 + j) * 4 + nt) * 4 + kt) * 64 + lane];
                acc = __builtin_amdgcn_mfma_f32_16x16x32_f16(ae[kt], g, acc, 0, 0, 0);
            }
            #pragma unroll
            for (int r = 0; r < 4; ++r)
                hxG[(size_t)b * 2048 + j * 1024 + (qd * 4 + r) * 64 + nt * 16 + lm] = (_Float16)acc[r];
        }
    }
}

// ================= FALLBACK: round-4 fused kernel (used if ws too small) ==========
template<int MT>
__device__ __forceinline__ void edge_class(
    const half8 (&fa)[MT], int ebase,
    const _Float16* __restrict__ hxsel,
    const unsigned char* __restrict__ esS, const unsigned char* __restrict__ erS,
    _Float16* __restrict__ hid0, _Float16* __restrict__ hid1,
    float* __restrict__ zbuf,
    const half8* __restrict__ W1F_lj, const float* __restrict__ B1_lj,
    const half8* __restrict__ W2F_lj,
    int lane, int qd, int lm)
{
    half8 w0 = W1F_lj[lane], w1v = W1F_lj[64 + lane], w2v = W1F_lj[128 + lane];
    float bi0 = B1_lj[lm], bi1 = B1_lj[16 + lm], bi2 = B1_lj[32 + lm];
    half8 bk[4][2];
    #pragma unroll
    for (int nt = 0; nt < 4; ++nt) {
        bk[nt][0] = W2F_lj[nt * 128 + lane];
        bk[nt][1] = W2F_lj[nt * 128 + 64 + lane];
    }
    #pragma unroll
    for (int mt = 0; mt < MT; ++mt) {
        _Float16* hidb = (mt & 1) ? hid1 : hid0;
        floatx4 c0 = {0,0,0,0}, c1 = c0, c2 = c0;
        c0 = __builtin_amdgcn_mfma_f32_16x16x32_f16(fa[mt], w0,  c0, 0, 0, 0);
        c1 = __builtin_amdgcn_mfma_f32_16x16x32_f16(fa[mt], w1v, c1, 0, 0, 0);
        c2 = __builtin_amdgcn_mfma_f32_16x16x32_f16(fa[mt], w2v, c2, 0, 0, 0);
        #pragma unroll
        for (int r = 0; r < 4; ++r) {
            int row = qd * 4 + r;
            float v0 = c0[r] + bi0, v1 = c1[r] + bi1, v2 = c2[r] + bi2;
            v0 = v0 * __builtin_amdgcn_rcpf(1.f + __expf(-v0));
            v1 = v1 * __builtin_amdgcn_rcpf(1.f + __expf(-v1));
            v2 = v2 * __builtin_amdgcn_rcpf(1.f + __expf(-v2));
            hidb[row * 72 + lm]      = (_Float16)v0;
            hidb[row * 72 + 16 + lm] = (_Float16)v1;
            hidb[row * 72 + 32 + lm] = (_Float16)v2;
        }
        half8 a0 = *(const half8*)(hidb + lm * 72 + qd * 8);
        half8 a1 = *(const half8*)(hidb + lm * 72 + 32 + qd * 8);
        #pragma unroll
        for (int nt = 0; nt < 4; ++nt) {
            floatx4 acc = {0,0,0,0};
            acc = __builtin_amdgcn_mfma_f32_16x16x32_f16(a0, bk[nt][0], acc, 0, 0, 0);
            acc = __builtin_amdgcn_mfma_f32_16x16x32_f16(a1, bk[nt][1], acc, 0, 0, 0);
            #pragma unroll
            for (int r = 0; r < 4; ++r) {
                int e = ebase + mt * 16 + qd * 4 + r;
                int s = esS[e], rr = erS[e];
                float weh = acc[r] * (float)hxsel[s * 68 + nt * 16 + lm];
                atomicAdd(&zbuf[rr * 68 + nt * 16 + lm], weh);
            }
        }
    }
}

__global__ __launch_bounds__(256, 2)
void schnet_kernel(const void* __restrict__ rs,
                   const void* __restrict__ coords,
                   const int* __restrict__ same_s, const int* __restrict__ same_r,
                   const int* __restrict__ anti_s, const int* __restrict__ anti_r,
                   const int* __restrict__ ne_s,   const int* __restrict__ ne_r,
                   const char* __restrict__ wsB,
                   void* __restrict__ out, int Bn) {
    const int tid = threadIdx.x;
    const int wv = tid >> 6, lane = tid & 63;
    const int qd = lane >> 4, lm = lane & 15;
    const int f32 = *(const int*)(wsB + OFF_FLAG_B);

    __shared__ float dLA[4][304];
    __shared__ float zbufA[4][16 * 68];
    __shared__ _Float16 hxA[4][2 * 16 * 68];
    __shared__ _Float16 scrA[4][2304];
    __shared__ _Float16 nucS[4 * 68];
    __shared__ unsigned char esS[E_TOT], erS[E_TOT];

    const float*    B1  = (const float*)(wsB + OFF_B1_B);
    const float*    XT  = (const float*)(wsB + OFF_XT_B);
    const _Float16* H0F = (const _Float16*)(wsB + OFF_H0_B);
    const _Float16* YWF = (const _Float16*)(wsB + OFF_YW_B);
    const half8*    W1F = (const half8*)(wsB + OFF_W1_B);
    const half8*    W2F = (const half8*)(wsB + OFF_W2_B);
    const half8*    GWF = (const half8*)(wsB + OFF_GW_B);
    const half8*    HWF = (const half8*)(wsB + OFF_HW_B);

    for (int i = tid; i < E_TOT; i += 256) {
        int s, r;
        if (i < 112)      { s = same_s[i];       r = same_r[i]; }
        else if (i < 240) { s = anti_s[i - 112]; r = anti_r[i - 112]; }
        else              { s = ne_s[i - 240];   r = ne_r[i - 240]; }
        esS[i] = (unsigned char)s; erS[i] = (unsigned char)r;
    }
    for (int i = tid; i < NN * KD; i += 256)
        nucS[(i >> 6) * 68 + (i & 63)] = YWF[i];
    for (int i = tid; i < 4 * 2304; i += 256) ((_Float16*)scrA)[i] = (_Float16)0.f;
    __syncthreads();

    int b = blockIdx.x * 4 + wv;
    if (b >= Bn) b = Bn - 1;

    float*     dLw   = dLA[wv];
    float*     zbuf  = zbufA[wv];
    _Float16*  hxB   = hxA[wv];
    _Float16*  elecB = scrA[wv];
    _Float16*  hid0  = scrA[wv];
    _Float16*  hid1  = scrA[wv] + 1152;

    for (int e = lane; e < E_TOT; e += 64) {
        int s = esS[e], r = erS[e];
        long rb = ((long)b * NE + r) * 3;
        float bx = ldf(rs, rb + 0, f32), by = ldf(rs, rb + 1, f32), bz = ldf(rs, rb + 2, f32);
        float ax, ay, az;
        if (e < 240) {
            long sb = ((long)b * NE + s) * 3;
            ax = ldf(rs, sb + 0, f32); ay = ldf(rs, sb + 1, f32); az = ldf(rs, sb + 2, f32);
        } else {
            ax = ldf(coords, s * 3 + 0, f32); ay = ldf(coords, s * 3 + 1, f32); az = ldf(coords, s * 3 + 2, f32);
        }
        float dx = ax - bx, dy = ay - by, dz = az - bz;
        dLw[e] = sqrtf(dx * dx + dy * dy + dz * dz);
    }

    half8 faS[7], faA[8], faN[4];
    #pragma unroll
    for (int mt = 0; mt < 7; ++mt) faS[mt] = mkfeat(dLw[mt * 16 + lm], qd);
    #pragma unroll
    for (int mt = 0; mt < 8; ++mt) faA[mt] = mkfeat(dLw[112 + mt * 16 + lm], qd);
    #pragma unroll
    for (int mt = 0; mt < 4; ++mt) faN[mt] = mkfeat(dLw[240 + mt * 16 + lm], qd);

    floatx4 eacc[8];
    #pragma unroll
    for (int t = 0; t < 8; ++t) {
        float xv = XT[t * 16 + lm];
        eacc[t][0] = xv; eacc[t][1] = xv; eacc[t][2] = xv; eacc[t][3] = xv;
    }

    for (int i = lane; i < 2 * NE * KD; i += 64) {
        int j = i >> 10, s = (i >> 6) & 15, k = i & 63;
        hxB[j * 1088 + s * 68 + k] = H0F[j * 64 + k];
    }

    for (int l = 0; l < 3; ++l) {
        if (l > 0) {
            #pragma unroll
            for (int t = 0; t < 8; ++t)
                #pragma unroll
                for (int r = 0; r < 4; ++r)
                    elecB[(qd * 4 + r) * 136 + t * 16 + lm] = (_Float16)eacc[t][r];
            half8 ae[4];
            #pragma unroll
            for (int kt = 0; kt < 4; ++kt)
                ae[kt] = *(const half8*)(elecB + lm * 136 + kt * 32 + qd * 8);
            #pragma unroll
            for (int j = 0; j < 2; ++j) {
                int lj4 = (l - 1) * 2 + j;
                #pragma unroll
                for (int nt = 0; nt < 4; ++nt) {
                    const half8* Bb = HWF + (lj4 * 4 + nt) * 4 * 64;
                    floatx4 acc = {0,0,0,0};
                    #pragma unroll
                    for (int kt = 0; kt < 4; ++kt)
                        acc = __builtin_amdgcn_mfma_f32_16x16x32_f16(ae[kt], Bb[kt * 64 + lane], acc, 0, 0, 0);
                    #pragma unroll
                    for (int r = 0; r < 4; ++r)
                        hxB[j * 1088 + (qd * 4 + r) * 68 + nt * 16 + lm] = (_Float16)acc[r];
                }
            }
        }

        #pragma unroll
        for (int j = 0; j < 3; ++j) {
            const int lj = l * 3 + j;
            for (int i = lane; i < 16 * 68; i += 64) zbuf[i] = 0.f;

            const half8* W1F_lj = W1F + lj * 192;
            const float* B1_lj  = B1 + lj * 48;
            const half8* W2F_lj = W2F + lj * 512;
            if (j == 0)
                edge_class<7>(faS, 0,   hxB,        esS, erS, hid0, hid1, zbuf, W1F_lj, B1_lj, W2F_lj, lane, qd, lm);
            else if (j == 1)
                edge_class<8>(faA, 112, hxB + 1088, esS, erS, hid0, hid1, zbuf, W1F_lj, B1_lj, W2F_lj, lane, qd, lm);
            else
                edge_class<4>(faN, 240, nucS,       esS, erS, hid0, hid1, zbuf, W1F_lj, B1_lj, W2F_lj, lane, qd, lm);

            floatx4 za0a = *(const floatx4*)(zbuf + lm * 68 + qd * 8);
            floatx4 za0b = *(const floatx4*)(zbuf + lm * 68 + qd * 8 + 4);
            floatx4 za1a = *(const floatx4*)(zbuf + lm * 68 + 32 + qd * 8);
            floatx4 za1b = *(const floatx4*)(zbuf + lm * 68 + 32 + qd * 8 + 4);
            half8 A0, A1;
            #pragma unroll
            for (int ii = 0; ii < 4; ++ii) {
                A0[ii] = (_Float16)za0a[ii]; A0[4 + ii] = (_Float16)za0b[ii];
                A1[ii] = (_Float16)za1a[ii]; A1[4 + ii] = (_Float16)za1b[ii];
            }
            const half8* GWF_lj = GWF + lj * 1024;
            #pragma unroll
            for (int t = 0; t < 8; ++t) {
                half8 g0 = GWF_lj[t * 128 + lane];
                half8 g1 = GWF_lj[t * 128 + 64 + lane];
                eacc[t] = __builtin_amdgcn_mfma_f32_16x16x32_f16(A0, g0, eacc[t], 0, 0, 0);
                eacc[t] = __builtin_amdgcn_mfma_f32_16x16x32_f16(A1, g1, eacc[t], 0, 0, 0);
            }
        }
    }

    if (f32) {
        float* o = (float*)out + (long)b * (NE * DDIM);
        #pragma unroll
        for (int t = 0; t < 8; ++t)
            #pragma unroll
            for (int r = 0; r < 4; ++r)
                o[(qd * 4 + r) * 128 + t * 16 + lm] = eacc[t][r];
    } else {
        __hip_bfloat16* o = (__hip_bfloat16*)out + (long)b * (NE * DDIM);
        #pragma unroll
        for (int t = 0; t < 8; ++t)
            #pragma unroll
            for (int r = 0; r < 4; ++r)
                o[(qd * 4 + r) * 128 + t * 16 + lm] = __float2bfloat16(eacc[t][r]);
    }
}

extern "C" void kernel_launch(void* const* d_in, const int* in_sizes, int n_in,
                              void* d_out, int out_size, void* d_ws, size_t ws_size,
                              hipStream_t stream) {
    const void* rs     = d_in[0];
    const void* coords = d_in[1];
    const void* X_tab  = d_in[2];
    const void* Y_w    = d_in[3];
    const void* wW1    = d_in[4];
    const void* wb1    = d_in[5];
    const void* wW2    = d_in[6];
    const void* h0     = d_in[7];
    const void* hW     = d_in[8];
    const void* gW     = d_in[9];
    const int* same_s = (const int*)d_in[10];
    const int* same_r = (const int*)d_in[11];
    const int* anti_s = (const int*)d_in[12];
    const int* anti_r = (const int*)d_in[13];
    const int* ne_s   = (const int*)d_in[14];
    const int* ne_r   = (const int*)d_in[15];
    char* wsB = (char*)d_ws;

    const int Bn = in_sizes[0] / (NE * 3);

    detect_kernel<<<1, 256, 0, stream>>>((const unsigned short*)rs, wsB);
    prep_kernel<<<288, 256, 0, stream>>>(wW1, wb1, wW2, h0, hW, gW, Y_w, X_tab, wsB);

    // dynamic ws layout
    size_t offDL    = OFF_DYN_B;                          // f32 [Bn][304]
    size_t offZG    = offDL    + (size_t)Bn * 1216;       // f16 [Bn][3][1024]
    size_t offElecC = offZG    + (size_t)Bn * 6144;       // f32 [Bn][2048]
    size_t offHxG   = offElecC + (size_t)Bn * 8192;       // f16 [Bn][2][16][64]
    size_t need     = offHxG   + (size_t)Bn * 4096;

    if (ws_size >= need) {
        float*    dLG   = (float*)(wsB + offDL);
        _Float16* zG    = (_Float16*)(wsB + offZG);
        float*    elecC = (float*)(wsB + offElecC);
        _Float16* hxG   = (_Float16*)(wsB + offHxG);

        dist_kernel<<<(Bn * 304 + 255) / 256, 256, 0, stream>>>(
            rs, coords, same_s, same_r, anti_s, anti_r, ne_s, ne_r, wsB, dLG, Bn);

        dim3 eg(3, Bn);
        edge_kernel<0><<<eg, 256, 0, stream>>>(same_s, same_r, anti_s, anti_r, ne_s, ne_r,
                                               wsB, dLG, hxG, zG);
        tailhx_kernel<0, false><<<Bn, 256, 0, stream>>>(wsB, zG, elecC, hxG, d_out);

        edge_kernel<1><<<eg, 256, 0, stream>>>(same_s, same_r, anti_s, anti_r, ne_s, ne_r,
                                               wsB, dLG, hxG, zG);
        tailhx_kernel<1, false><<<Bn, 256, 0, stream>>>(wsB, zG, elecC, hxG, d_out);

        edge_kernel<2><<<eg, 256, 0, stream>>>(same_s, same_r, anti_s, anti_r, ne_s, ne_r,
                                               wsB, dLG, hxG, zG);
        tailhx_kernel<2, true><<<Bn, 256, 0, stream>>>(wsB, zG, elecC, hxG, d_out);
    } else {
        schnet_kernel<<<(Bn + 3) / 4, 256, 0, stream>>>(rs, coords, same_s, same_r, anti_s, anti_r,
                                                        ne_s, ne_r, wsB, d_out, Bn);
    }
}

// Round 10
// 271.006 us; speedup vs baseline: 3.0158x; 3.0158x over previous
//
#include <hip/hip_runtime.h>
#include <hip/hip_bf16.h>

#define NE 16
#define NN 4
#define DDIM 128
#define KD 64
#define HD 45
#define E_TOT 304

typedef _Float16 half8 __attribute__((ext_vector_type(8)));
typedef float floatx4 __attribute__((ext_vector_type(4)));

// ws byte offsets (static region)
#define OFF_FLAG_B 0
#define OFF_B1_B   64       // fp32 [9][48] (pad cols 45..47 = 0)
#define OFF_XT_B   1792     // fp32 [128]
#define OFF_H0_B   2304     // f16 [2][64]
#define OFF_YW_B   2560     // f16 [4][64]
#define OFF_W1_B   3072     // f16 frag [9][3nt][512]
#define OFF_W2_B   30720    // f16 frag [9][4nt][2kt][512] (rows 45..63 zero)
#define OFF_GW_B   104448   // f16 frag [9][8nt][2kt][512]
#define OFF_HW_B   251904   // f16 frag [4][4nt][4kt][512]
#define OFF_RL_B   317440   // int rl[3][16][8]: e | (s<<16)
#define OFF_DYN_B  318976   // dynamic per-B buffers follow

__device__ __forceinline__ float ldf(const void* p, long i, int f32) {
    if (f32) return ((const float*)p)[i];
    unsigned int u = ((unsigned int)((const unsigned short*)p)[i]) << 16;
    return __uint_as_float(u);
}

__global__ void detect_kernel(const unsigned short* rs16, char* wsB) {
    __shared__ int bad;
    if (threadIdx.x == 0) bad = 0;
    __syncthreads();
    for (int i = threadIdx.x; i < 2048; i += 256) {
        unsigned int u = ((unsigned int)rs16[i]) << 16;
        float v = __uint_as_float(u);
        if (!(fabsf(v) < 1e6f)) atomicOr(&bad, 1);
    }
    __syncthreads();
    if (threadIdx.x == 0) *(int*)(wsB + OFF_FLAG_B) = bad ? 1 : 0;
}

__global__ void prep_kernel(const void* w1, const void* b1, const void* w2, const void* h0,
                            const void* hW, const void* gW, const void* Yw, const void* Xt,
                            char* wsB) {
    const int f32 = *(const int*)(wsB + OFF_FLAG_B);
    int i = blockIdx.x * 256 + threadIdx.x;
    _Float16* W1F = (_Float16*)(wsB + OFF_W1_B);
    _Float16* W2F = (_Float16*)(wsB + OFF_W2_B);
    _Float16* GWF = (_Float16*)(wsB + OFF_GW_B);
    _Float16* HWF = (_Float16*)(wsB + OFF_HW_B);
    float*    B1  = (float*)(wsB + OFF_B1_B);
    float*    XT  = (float*)(wsB + OFF_XT_B);
    _Float16* H0F = (_Float16*)(wsB + OFF_H0_B);
    _Float16* YWF = (_Float16*)(wsB + OFF_YW_B);

    if (i < 13824) {  // W1 frags
        int lj = i / 1536, rem = i % 1536;
        int nt = rem >> 9, lane = (rem & 511) >> 3, e = rem & 7;
        int row = ((lane >> 4) << 3) + e;
        int col = (nt << 4) + (lane & 15);
        W1F[i] = (_Float16)((col < 45) ? ldf(w1, lj * 1440 + row * 45 + col, f32) : 0.f);
    }
    if (i < 36864) {  // W2 frags (rows >= 45 zero)
        int lj = i / 4096, rem = i & 4095;
        int nt = rem >> 10, kt = (rem >> 9) & 1, lane = (rem & 511) >> 3, e = rem & 7;
        int row = (kt << 5) + ((lane >> 4) << 3) + e;
        int col = (nt << 4) + (lane & 15);
        W2F[i] = (_Float16)((row < 45) ? ldf(w2, lj * 2880 + row * 64 + col, f32) : 0.f);
    }
    if (i < 73728) {  // gW frags
        int lj = i >> 13, rem = i & 8191;
        int nt = rem >> 10, kt = (rem >> 9) & 1, lane = (rem & 511) >> 3, e = rem & 7;
        int row = (kt << 5) + ((lane >> 4) << 3) + e;
        int col = (nt << 4) + (lane & 15);
        GWF[i] = (_Float16)ldf(gW, lj * 8192 + row * 128 + col, f32);
    }
    if (i < 32768) {  // hW frags
        int lj = i >> 13, rem = i & 8191;
        int nt = rem >> 11, kt = (rem >> 9) & 3, lane = (rem & 511) >> 3, e = rem & 7;
        int row = (kt << 5) + ((lane >> 4) << 3) + e;
        int col = (nt << 4) + (lane & 15);
        HWF[i] = (_Float16)ldf(hW, lj * 8192 + row * 64 + col, f32);
    }
    if (i < 432) { int lj = i / 48, n = i % 48; B1[i] = (n < 45) ? ldf(b1, lj * 45 + n, f32) : 0.f; }
    if (i < 128) XT[i] = ldf(Xt, i, f32);
    if (i < 128) H0F[i] = (_Float16)ldf(h0, i, f32);
    if (i < 256) YWF[i] = (_Float16)ldf(Yw, i, f32);
}

// receiver->edge list with packed sender: entry = e | (s<<16); counts are exactly 7/8/4
__global__ void rlbuild_kernel(const int* __restrict__ same_s, const int* __restrict__ same_r,
                               const int* __restrict__ anti_s, const int* __restrict__ anti_r,
                               const int* __restrict__ ne_s,   const int* __restrict__ ne_r,
                               char* wsB) {
    int lane = threadIdx.x;
    if (lane >= 48) return;
    int j = lane >> 4, r = lane & 15;
    int* rl = (int*)(wsB + OFF_RL_B) + lane * 8;
    int base = (j == 0) ? 0 : ((j == 1) ? 112 : 240);
    int cnt  = (j == 0) ? 112 : ((j == 1) ? 128 : 64);
    const int* rr = (j == 0) ? same_r : ((j == 1) ? anti_r : ne_r);
    const int* ss = (j == 0) ? same_s : ((j == 1) ? anti_s : ne_s);
    int n = 0;
    for (int i = 0; i < cnt && n < 8; ++i)
        if (rr[i] == r) { rl[n++] = (base + i) | (ss[i] << 16); }
    for (; n < 8; ++n) rl[n] = base;
}

__global__ void dist_kernel(const void* __restrict__ rs, const void* __restrict__ coords,
                            const int* __restrict__ same_s, const int* __restrict__ same_r,
                            const int* __restrict__ anti_s, const int* __restrict__ anti_r,
                            const int* __restrict__ ne_s,   const int* __restrict__ ne_r,
                            const char* __restrict__ wsB, float* __restrict__ dLG, int Bn) {
    const int f32 = *(const int*)(wsB + OFF_FLAG_B);
    int idx = blockIdx.x * 256 + threadIdx.x;
    if (idx >= Bn * 304) return;
    int b = idx / 304, e = idx - b * 304;
    int s, r;
    if (e < 112)      { s = same_s[e];       r = same_r[e]; }
    else if (e < 240) { s = anti_s[e - 112]; r = anti_r[e - 112]; }
    else              { s = ne_s[e - 240];   r = ne_r[e - 240]; }
    long rb = ((long)b * NE + r) * 3;
    float bx = ldf(rs, rb + 0, f32), by = ldf(rs, rb + 1, f32), bz = ldf(rs, rb + 2, f32);
    float ax, ay, az;
    if (e < 240) {
        long sb = ((long)b * NE + s) * 3;
        ax = ldf(rs, sb + 0, f32); ay = ldf(rs, sb + 1, f32); az = ldf(rs, sb + 2, f32);
    } else {
        ax = ldf(coords, s * 3 + 0, f32); ay = ldf(coords, s * 3 + 1, f32); az = ldf(coords, s * 3 + 2, f32);
    }
    float dx = ax - bx, dy = ay - by, dz = az - bz;
    dLG[idx] = sqrtf(dx * dx + dy * dy + dz * dz);
}

__device__ __forceinline__ half8 mkfeat(float d, int qd) {
    float env = d * d * __expf(-d);
    half8 a;
    #pragma unroll
    for (int ii = 0; ii < 8; ++ii) {
        float qf = (float)(qd * 8 + ii) * (1.f / 31.f);
        float mu = 10.f * qf * qf;
        float isg = 7.f * __builtin_amdgcn_rcpf(1.f + 10.f * qf);
        float tt = (d - mu) * isg;
        a[ii] = (_Float16)(env * __expf(-tt * tt));
    }
    return a;
}

// ====== weall: one wave = one (b, L, t) tile; ALL 3 layers at once; hx-independent ======
__global__ __launch_bounds__(256, 4)
void weall_kernel(const char* __restrict__ wsB, const float* __restrict__ dLG,
                  _Float16* __restrict__ weG, int ntask) {
    const int wv = threadIdx.x >> 6, lane = threadIdx.x & 63;
    const int qd = lane >> 4, lm = lane & 15;
    __shared__ __align__(16) _Float16 hidA[4][1024];
    _Float16* hid = hidA[wv];
    int task = blockIdx.x * 4 + wv;
    if (task >= ntask) return;
    const int b = task / 57, lt = task - b * 57;
    const int L = lt / 19, t = lt - L * 19;
    const int j = (t < 7) ? 0 : ((t < 15) ? 1 : 2);
    const int lj = L * 3 + j;

    const half8* W1F = (const half8*)(wsB + OFF_W1_B);
    const half8* W2F = (const half8*)(wsB + OFF_W2_B);
    const float* B1  = (const float*)(wsB + OFF_B1_B);

    const half8* W1F_lj = W1F + lj * 192;
    half8 w0 = W1F_lj[lane], w1v = W1F_lj[64 + lane], w2v = W1F_lj[128 + lane];
    float bi0 = B1[lj * 48 + lm], bi1 = B1[lj * 48 + 16 + lm], bi2 = B1[lj * 48 + 32 + lm];
    float d = dLG[(size_t)b * 304 + t * 16 + lm];

    {   // zero own hid slice (cols 45..63 must stay finite zero)
        half8 z8 = {0,0,0,0,0,0,0,0};
        *(half8*)(hid + lane * 8) = z8;
        *(half8*)(hid + 512 + lane * 8) = z8;
    }

    half8 fa = mkfeat(d, qd);
    floatx4 c0 = {0.f,0.f,0.f,0.f}, c1 = c0, c2 = c0;
    c0 = __builtin_amdgcn_mfma_f32_16x16x32_f16(fa, w0,  c0, 0, 0, 0);
    c1 = __builtin_amdgcn_mfma_f32_16x16x32_f16(fa, w1v, c1, 0, 0, 0);
    c2 = __builtin_amdgcn_mfma_f32_16x16x32_f16(fa, w2v, c2, 0, 0, 0);
    #pragma unroll
    for (int r = 0; r < 4; ++r) {
        int row = qd * 4 + r;
        float v0 = c0[r] + bi0, v1 = c1[r] + bi1, v2 = c2[r] + bi2;
        v0 = v0 * __builtin_amdgcn_rcpf(1.f + __expf(-v0));
        v1 = v1 * __builtin_amdgcn_rcpf(1.f + __expf(-v1));
        v2 = v2 * __builtin_amdgcn_rcpf(1.f + __expf(-v2));
        hid[row * 64 + lm]      = (_Float16)v0;
        hid[row * 64 + 16 + lm] = (_Float16)v1;
        hid[row * 64 + 32 + lm] = (_Float16)v2;
    }
    half8 a0 = *(const half8*)(hid + lm * 64 + qd * 8);
    half8 a1 = *(const half8*)(hid + lm * 64 + 32 + qd * 8);

    const half8* W2F_lj = W2F + lj * 512;
    _Float16* wrow = weG + ((size_t)(b * 3 + L) * 304 + (size_t)(t * 16)) * 64;
    #pragma unroll
    for (int nt = 0; nt < 4; ++nt) {
        half8 bk0 = W2F_lj[nt * 128 + lane], bk1 = W2F_lj[nt * 128 + 64 + lane];
        floatx4 acc = {0.f,0.f,0.f,0.f};
        acc = __builtin_amdgcn_mfma_f32_16x16x32_f16(a0, bk0, acc, 0, 0, 0);
        acc = __builtin_amdgcn_mfma_f32_16x16x32_f16(a1, bk1, acc, 0, 0, 0);
        const int k = nt * 16 + lm;
        #pragma unroll
        for (int r = 0; r < 4; ++r)
            wrow[(size_t)(qd * 4 + r) * 64 + k] = (_Float16)acc[r];
    }
}

// ====== tailhx_zg: block = b; gather(z = sum we*hx) -> tail MFMA -> hx for next layer ======
template<int L, bool LAST>
__global__ __launch_bounds__(256, 4)
void tailhx_kernel(const char* __restrict__ wsB,
                   const _Float16* __restrict__ weG,
                   float* __restrict__ elecC, _Float16* __restrict__ hxG,
                   void* __restrict__ out) {
    const int b = blockIdx.x;
    const int tid = threadIdx.x;
    const int q = tid >> 6, lane = tid & 63;
    const int qd = lane >> 4, lm = lane & 15;
    const int f32 = *(const int*)(wsB + OFF_FLAG_B);

    __shared__ float zS[3 * 16 * 68];                  // 13056 B (stride 68: conflict-free frags)
    __shared__ _Float16 hxS[2 * 1024];                 // [j][s][64]
    __shared__ _Float16 nucS[256];                     // [s][64]
    __shared__ int rlS[384];
    __shared__ __align__(16) _Float16 elecB[16 * 136];

    const half8* GWF = (const half8*)(wsB + OFF_GW_B);
    const half8* HWF = (const half8*)(wsB + OFF_HW_B);
    const float* XT  = (const float*)(wsB + OFF_XT_B);
    const _Float16* H0F = (const _Float16*)(wsB + OFF_H0_B);
    const _Float16* YWF = (const _Float16*)(wsB + OFF_YW_B);

    // ---- stage ----
    for (int i = tid; i < 384; i += 256) rlS[i] = ((const int*)(wsB + OFF_RL_B))[i];
    if (L == 0) {
        for (int i = tid; i < 2048; i += 256) hxS[i] = H0F[((i >> 10) << 6) + (i & 63)];
    } else {
        int i = tid * 8;
        *(half8*)(hxS + i) = *(const half8*)(hxG + (size_t)b * 2048 + i);
    }
    if (tid < 256) nucS[tid] = YWF[tid];
    __syncthreads();

    // ---- gather: z[j][r][k] = sum_e we[e][k]*hx[s_e][k]; no atomics ----
    const _Float16* web = weG + (size_t)(b * 3 + L) * 304 * 64;
    #pragma unroll
    for (int rr4 = 0; rr4 < 4; ++rr4) {
        const int r = q * 4 + rr4;
        #pragma unroll
        for (int j = 0; j < 3; ++j) {
            const int cnt = (j == 0) ? 7 : ((j == 1) ? 8 : 4);
            const int* rlj = rlS + (j * 16 + r) * 8;
            float acc = 0.f;
            #pragma unroll
            for (int i = 0; i < 8; ++i) {
                if (i < cnt) {
                    int pk = rlj[i];
                    int e = pk & 0xFFFF, s = pk >> 16;
                    float wev = (float)web[(size_t)e * 64 + lane];
                    float hxv = (j == 2) ? (float)nucS[s * 64 + lane]
                                         : (float)hxS[j * 1024 + s * 64 + lane];
                    acc += wev * hxv;
                }
            }
            zS[j * 1088 + r * 68 + lane] = acc;
        }
    }
    __syncthreads();

    // ---- tail: elec += z_cat @ gW_cat ----
    half8 zf[6];
    #pragma unroll
    for (int jj = 0; jj < 6; ++jj) {
        int j = jj >> 1, kh = jj & 1;
        const float* zr = zS + j * 1088 + lm * 68 + kh * 32 + qd * 8;
        floatx4 va = *(const floatx4*)zr;
        floatx4 vb = *(const floatx4*)(zr + 4);
        #pragma unroll
        for (int ii = 0; ii < 4; ++ii) { zf[jj][ii] = (_Float16)va[ii]; zf[jj][4 + ii] = (_Float16)vb[ii]; }
    }
    #pragma unroll
    for (int u = 0; u < 2; ++u) {
        int t2 = q * 2 + u;
        floatx4 acc;
        if (L == 0) {
            float xv = XT[t2 * 16 + lm];
            acc[0] = xv; acc[1] = xv; acc[2] = xv; acc[3] = xv;
        } else {
            acc = *(const floatx4*)(elecC + (size_t)b * 2048 + (size_t)((qd * 8 + t2) * 16 + lm) * 4);
        }
        #pragma unroll
        for (int jj = 0; jj < 6; ++jj) {
            int j = jj >> 1, kh = jj & 1;
            half8 g = GWF[(L * 3 + j) * 1024 + t2 * 128 + kh * 64 + lane];
            acc = __builtin_amdgcn_mfma_f32_16x16x32_f16(zf[jj], g, acc, 0, 0, 0);
        }
        if (LAST) {
            if (f32) {
                float* o = (float*)out + (size_t)b * 2048;
                #pragma unroll
                for (int r = 0; r < 4; ++r) o[(qd * 4 + r) * 128 + t2 * 16 + lm] = acc[r];
            } else {
                __hip_bfloat16* o = (__hip_bfloat16*)out + (size_t)b * 2048;
                #pragma unroll
                for (int r = 0; r < 4; ++r) o[(qd * 4 + r) * 128 + t2 * 16 + lm] = __float2bfloat16(acc[r]);
            }
        } else {
            *(floatx4*)(elecC + (size_t)b * 2048 + (size_t)((qd * 8 + t2) * 16 + lm) * 4) = acc;
            #pragma unroll
            for (int r = 0; r < 4; ++r)
                elecB[(qd * 4 + r) * 136 + t2 * 16 + lm] = (_Float16)acc[r];
        }
    }
    if (!LAST) {
        __syncthreads();
        half8 ae[4];
        #pragma unroll
        for (int kt = 0; kt < 4; ++kt)
            ae[kt] = *(const half8*)(elecB + lm * 136 + kt * 32 + qd * 8);
        #pragma unroll
        for (int u = 0; u < 2; ++u) {
            int idx = q * 2 + u;
            int j = idx >> 2, nt = idx & 3;
            floatx4 acc = {0.f,0.f,0.f,0.f};
            #pragma unroll
            for (int kt = 0; kt < 4; ++kt) {
                half8 g = HWF[(size_t)(((L * 2 + j) * 4 + nt) * 4 + kt) * 64 + lane];
                acc = __builtin_amdgcn_mfma_f32_16x16x32_f16(ae[kt], g, acc, 0, 0, 0);
            }
            #pragma unroll
            for (int r = 0; r < 4; ++r)
                hxG[(size_t)b * 2048 + j * 1024 + (qd * 4 + r) * 64 + nt * 16 + lm] = (_Float16)acc[r];
        }
    }
}

// ================= FALLBACK: round-4 fused kernel (used if ws too small) ==========
template<int MT>
__device__ __forceinline__ void edge_class(
    const half8 (&fa)[MT], int ebase,
    const _Float16* __restrict__ hxsel,
    const unsigned char* __restrict__ esS, const unsigned char* __restrict__ erS,
    _Float16* __restrict__ hid0, _Float16* __restrict__ hid1,
    float* __restrict__ zbuf,
    const half8* __restrict__ W1F_lj, const float* __restrict__ B1_lj,
    const half8* __restrict__ W2F_lj,
    int lane, int qd, int lm)
{
    half8 w0 = W1F_lj[lane], w1v = W1F_lj[64 + lane], w2v = W1F_lj[128 + lane];
    float bi0 = B1_lj[lm], bi1 = B1_lj[16 + lm], bi2 = B1_lj[32 + lm];
    half8 bk[4][2];
    #pragma unroll
    for (int nt = 0; nt < 4; ++nt) {
        bk[nt][0] = W2F_lj[nt * 128 + lane];
        bk[nt][1] = W2F_lj[nt * 128 + 64 + lane];
    }
    #pragma unroll
    for (int mt = 0; mt < MT; ++mt) {
        _Float16* hidb = (mt & 1) ? hid1 : hid0;
        floatx4 c0 = {0,0,0,0}, c1 = c0, c2 = c0;
        c0 = __builtin_amdgcn_mfma_f32_16x16x32_f16(fa[mt], w0,  c0, 0, 0, 0);
        c1 = __builtin_amdgcn_mfma_f32_16x16x32_f16(fa[mt], w1v, c1, 0, 0, 0);
        c2 = __builtin_amdgcn_mfma_f32_16x16x32_f16(fa[mt], w2v, c2, 0, 0, 0);
        #pragma unroll
        for (int r = 0; r < 4; ++r) {
            int row = qd * 4 + r;
            float v0 = c0[r] + bi0, v1 = c1[r] + bi1, v2 = c2[r] + bi2;
            v0 = v0 * __builtin_amdgcn_rcpf(1.f + __expf(-v0));
            v1 = v1 * __builtin_amdgcn_rcpf(1.f + __expf(-v1));
            v2 = v2 * __builtin_amdgcn_rcpf(1.f + __expf(-v2));
            hidb[row * 72 + lm]      = (_Float16)v0;
            hidb[row * 72 + 16 + lm] = (_Float16)v1;
            hidb[row * 72 + 32 + lm] = (_Float16)v2;
        }
        half8 a0 = *(const half8*)(hidb + lm * 72 + qd * 8);
        half8 a1 = *(const half8*)(hidb + lm * 72 + 32 + qd * 8);
        #pragma unroll
        for (int nt = 0; nt < 4; ++nt) {
            floatx4 acc = {0,0,0,0};
            acc = __builtin_amdgcn_mfma_f32_16x16x32_f16(a0, bk[nt][0], acc, 0, 0, 0);
            acc = __builtin_amdgcn_mfma_f32_16x16x32_f16(a1, bk[nt][1], acc, 0, 0, 0);
            #pragma unroll
            for (int r = 0; r < 4; ++r) {
                int e = ebase + mt * 16 + qd * 4 + r;
                int s = esS[e], rr = erS[e];
                float weh = acc[r] * (float)hxsel[s * 68 + nt * 16 + lm];
                atomicAdd(&zbuf[rr * 68 + nt * 16 + lm], weh);
            }
        }
    }
}

__global__ __launch_bounds__(256, 2)
void schnet_kernel(const void* __restrict__ rs,
                   const void* __restrict__ coords,
                   const int* __restrict__ same_s, const int* __restrict__ same_r,
                   const int* __restrict__ anti_s, const int* __restrict__ anti_r,
                   const int* __restrict__ ne_s,   const int* __restrict__ ne_r,
                   const char* __restrict__ wsB,
                   void* __restrict__ out, int Bn) {
    const int tid = threadIdx.x;
    const int wv = tid >> 6, lane = tid & 63;
    const int qd = lane >> 4, lm = lane & 15;
    const int f32 = *(const int*)(wsB + OFF_FLAG_B);

    __shared__ float dLA[4][304];
    __shared__ float zbufA[4][16 * 68];
    __shared__ _Float16 hxA[4][2 * 16 * 68];
    __shared__ _Float16 scrA[4][2304];
    __shared__ _Float16 nucS[4 * 68];
    __shared__ unsigned char esS[E_TOT], erS[E_TOT];

    const float*    B1  = (const float*)(wsB + OFF_B1_B);
    const float*    XT  = (const float*)(wsB + OFF_XT_B);
    const _Float16* H0F = (const _Float16*)(wsB + OFF_H0_B);
    const _Float16* YWF = (const _Float16*)(wsB + OFF_YW_B);
    const half8*    W1F = (const half8*)(wsB + OFF_W1_B);
    const half8*    W2F = (const half8*)(wsB + OFF_W2_B);
    const half8*    GWF = (const half8*)(wsB + OFF_GW_B);
    const half8*    HWF = (const half8*)(wsB + OFF_HW_B);

    for (int i = tid; i < E_TOT; i += 256) {
        int s, r;
        if (i < 112)      { s = same_s[i];       r = same_r[i]; }
        else if (i < 240) { s = anti_s[i - 112]; r = anti_r[i - 112]; }
        else              { s = ne_s[i - 240];   r = ne_r[i - 240]; }
        esS[i] = (unsigned char)s; erS[i] = (unsigned char)r;
    }
    for (int i = tid; i < NN * KD; i += 256)
        nucS[(i >> 6) * 68 + (i & 63)] = YWF[i];
    for (int i = tid; i < 4 * 2304; i += 256) ((_Float16*)scrA)[i] = (_Float16)0.f;
    __syncthreads();

    int b = blockIdx.x * 4 + wv;
    if (b >= Bn) b = Bn - 1;

    float*     dLw   = dLA[wv];
    float*     zbuf  = zbufA[wv];
    _Float16*  hxB   = hxA[wv];
    _Float16*  elecB = scrA[wv];
    _Float16*  hid0  = scrA[wv];
    _Float16*  hid1  = scrA[wv] + 1152;

    for (int e = lane; e < E_TOT; e += 64) {
        int s = esS[e], r = erS[e];
        long rb = ((long)b * NE + r) * 3;
        float bx = ldf(rs, rb + 0, f32), by = ldf(rs, rb + 1, f32), bz = ldf(rs, rb + 2, f32);
        float ax, ay, az;
        if (e < 240) {
            long sb = ((long)b * NE + s) * 3;
            ax = ldf(rs, sb + 0, f32); ay = ldf(rs, sb + 1, f32); az = ldf(rs, sb + 2, f32);
        } else {
            ax = ldf(coords, s * 3 + 0, f32); ay = ldf(coords, s * 3 + 1, f32); az = ldf(coords, s * 3 + 2, f32);
        }
        float dx = ax - bx, dy = ay - by, dz = az - bz;
        dLw[e] = sqrtf(dx * dx + dy * dy + dz * dz);
    }

    half8 faS[7], faA[8], faN[4];
    #pragma unroll
    for (int mt = 0; mt < 7; ++mt) faS[mt] = mkfeat(dLw[mt * 16 + lm], qd);
    #pragma unroll
    for (int mt = 0; mt < 8; ++mt) faA[mt] = mkfeat(dLw[112 + mt * 16 + lm], qd);
    #pragma unroll
    for (int mt = 0; mt < 4; ++mt) faN[mt] = mkfeat(dLw[240 + mt * 16 + lm], qd);

    floatx4 eacc[8];
    #pragma unroll
    for (int t = 0; t < 8; ++t) {
        float xv = XT[t * 16 + lm];
        eacc[t][0] = xv; eacc[t][1] = xv; eacc[t][2] = xv; eacc[t][3] = xv;
    }

    for (int i = lane; i < 2 * NE * KD; i += 64) {
        int j = i >> 10, s = (i >> 6) & 15, k = i & 63;
        hxB[j * 1088 + s * 68 + k] = H0F[j * 64 + k];
    }

    for (int l = 0; l < 3; ++l) {
        if (l > 0) {
            #pragma unroll
            for (int t = 0; t < 8; ++t)
                #pragma unroll
                for (int r = 0; r < 4; ++r)
                    elecB[(qd * 4 + r) * 136 + t * 16 + lm] = (_Float16)eacc[t][r];
            half8 ae[4];
            #pragma unroll
            for (int kt = 0; kt < 4; ++kt)
                ae[kt] = *(const half8*)(elecB + lm * 136 + kt * 32 + qd * 8);
            #pragma unroll
            for (int j = 0; j < 2; ++j) {
                int lj4 = (l - 1) * 2 + j;
                #pragma unroll
                for (int nt = 0; nt < 4; ++nt) {
                    const half8* Bb = HWF + (lj4 * 4 + nt) * 4 * 64;
                    floatx4 acc = {0,0,0,0};
                    #pragma unroll
                    for (int kt = 0; kt < 4; ++kt)
                        acc = __builtin_amdgcn_mfma_f32_16x16x32_f16(ae[kt], Bb[kt * 64 + lane], acc, 0, 0, 0);
                    #pragma unroll
                    for (int r = 0; r < 4; ++r)
                        hxB[j * 1088 + (qd * 4 + r) * 68 + nt * 16 + lm] = (_Float16)acc[r];
                }
            }
        }

        #pragma unroll
        for (int j = 0; j < 3; ++j) {
            const int lj = l * 3 + j;
            for (int i = lane; i < 16 * 68; i += 64) zbuf[i] = 0.f;

            const half8* W1F_lj = W1F + lj * 192;
            const float* B1_lj  = B1 + lj * 48;
            const half8* W2F_lj = W2F + lj * 512;
            if (j == 0)
                edge_class<7>(faS, 0,   hxB,        esS, erS, hid0, hid1, zbuf, W1F_lj, B1_lj, W2F_lj, lane, qd, lm);
            else if (j == 1)
                edge_class<8>(faA, 112, hxB + 1088, esS, erS, hid0, hid1, zbuf, W1F_lj, B1_lj, W2F_lj, lane, qd, lm);
            else
                edge_class<4>(faN, 240, nucS,       esS, erS, hid0, hid1, zbuf, W1F_lj, B1_lj, W2F_lj, lane, qd, lm);

            floatx4 za0a = *(const floatx4*)(zbuf + lm * 68 + qd * 8);
            floatx4 za0b = *(const floatx4*)(zbuf + lm * 68 + qd * 8 + 4);
            floatx4 za1a = *(const floatx4*)(zbuf + lm * 68 + 32 + qd * 8);
            floatx4 za1b = *(const floatx4*)(zbuf + lm * 68 + 32 + qd * 8 + 4);
            half8 A0, A1;
            #pragma unroll
            for (int ii = 0; ii < 4; ++ii) {
                A0[ii] = (_Float16)za0a[ii]; A0[4 + ii] = (_Float16)za0b[ii];
                A1[ii] = (_Float16)za1a[ii]; A1[4 + ii] = (_Float16)za1b[ii];
            }
            const half8* GWF_lj = GWF + lj * 1024;
            #pragma unroll
            for (int t = 0; t < 8; ++t) {
                half8 g0 = GWF_lj[t * 128 + lane];
                half8 g1 = GWF_lj[t * 128 + 64 + lane];
                eacc[t] = __builtin_amdgcn_mfma_f32_16x16x32_f16(A0, g0, eacc[t], 0, 0, 0);
                eacc[t] = __builtin_amdgcn_mfma_f32_16x16x32_f16(A1, g1, eacc[t], 0, 0, 0);
            }
        }
    }

    if (f32) {
        float* o = (float*)out + (long)b * (NE * DDIM);
        #pragma unroll
        for (int t = 0; t < 8; ++t)
            #pragma unroll
            for (int r = 0; r < 4; ++r)
                o[(qd * 4 + r) * 128 + t * 16 + lm] = eacc[t][r];
    } else {
        __hip_bfloat16* o = (__hip_bfloat16*)out + (long)b * (NE * DDIM);
        #pragma unroll
        for (int t = 0; t < 8; ++t)
            #pragma unroll
            for (int r = 0; r < 4; ++r)
                o[(qd * 4 + r) * 128 + t * 16 + lm] = __float2bfloat16(eacc[t][r]);
    }
}

extern "C" void kernel_launch(void* const* d_in, const int* in_sizes, int n_in,
                              void* d_out, int out_size, void* d_ws, size_t ws_size,
                              hipStream_t stream) {
    const void* rs     = d_in[0];
    const void* coords = d_in[1];
    const void* X_tab  = d_in[2];
    const void* Y_w    = d_in[3];
    const void* wW1    = d_in[4];
    const void* wb1    = d_in[5];
    const void* wW2    = d_in[6];
    const void* h0     = d_in[7];
    const void* hW     = d_in[8];
    const void* gW     = d_in[9];
    const int* same_s = (const int*)d_in[10];
    const int* same_r = (const int*)d_in[11];
    const int* anti_s = (const int*)d_in[12];
    const int* anti_r = (const int*)d_in[13];
    const int* ne_s   = (const int*)d_in[14];
    const int* ne_r   = (const int*)d_in[15];
    char* wsB = (char*)d_ws;

    const int Bn = in_sizes[0] / (NE * 3);

    detect_kernel<<<1, 256, 0, stream>>>((const unsigned short*)rs, wsB);
    prep_kernel<<<288, 256, 0, stream>>>(wW1, wb1, wW2, h0, hW, gW, Y_w, X_tab, wsB);

    // dynamic ws layout
    size_t offDL    = OFF_DYN_B;                          // f32 [Bn][304]
    size_t offWe    = offDL    + (size_t)Bn * 1216;       // f16 [Bn][3][304][64]
    size_t offElecC = offWe    + (size_t)Bn * 116736;     // f32 [Bn][2048]
    size_t offHxG   = offElecC + (size_t)Bn * 8192;       // f16 [Bn][2][16][64]
    size_t need     = offHxG   + (size_t)Bn * 4096;

    if (ws_size >= need) {
        float*    dLG   = (float*)(wsB + offDL);
        _Float16* weG   = (_Float16*)(wsB + offWe);
        float*    elecC = (float*)(wsB + offElecC);
        _Float16* hxG   = (_Float16*)(wsB + offHxG);

        rlbuild_kernel<<<1, 64, 0, stream>>>(same_s, same_r, anti_s, anti_r, ne_s, ne_r, wsB);
        dist_kernel<<<(Bn * 304 + 255) / 256, 256, 0, stream>>>(
            rs, coords, same_s, same_r, anti_s, anti_r, ne_s, ne_r, wsB, dLG, Bn);

        const int nWe = Bn * 57;
        weall_kernel<<<(nWe + 3) / 4, 256, 0, stream>>>(wsB, dLG, weG, nWe);

        tailhx_kernel<0, false><<<Bn, 256, 0, stream>>>(wsB, weG, elecC, hxG, d_out);
        tailhx_kernel<1, false><<<Bn, 256, 0, stream>>>(wsB, weG, elecC, hxG, d_out);
        tailhx_kernel<2, true><<<Bn, 256, 0, stream>>>(wsB, weG, elecC, hxG, d_out);
    } else {
        schnet_kernel<<<(Bn + 3) / 4, 256, 0, stream>>>(rs, coords, same_s, same_r, anti_s, anti_r,
                                                        ne_s, ne_r, wsB, d_out, Bn);
    }
}

// Round 11
// 267.675 us; speedup vs baseline: 3.0533x; 1.0124x over previous
//
#include <hip/hip_runtime.h>
#include <hip/hip_bf16.h>

#define NE 16
#define NN 4
#define DDIM 128
#define KD 64
#define HD 45
#define E_TOT 304

typedef _Float16 half8 __attribute__((ext_vector_type(8)));
typedef float floatx4 __attribute__((ext_vector_type(4)));

// ws byte offsets (static region)
#define OFF_FLAG_B 0
#define OFF_B1_B   64       // fp32 [9][48] (pad cols 45..47 = 0)
#define OFF_XT_B   1792     // fp32 [128]
#define OFF_H0_B   2304     // f16 [2][64]
#define OFF_YW_B   2560     // f16 [4][64]
#define OFF_W1_B   3072     // f16 frag [9][3nt][512]
#define OFF_W2_B   30720    // f16 frag [9][4nt][2kt][512] (rows 45..63 zero)
#define OFF_GW_B   104448   // f16 frag [9][8nt][2kt][512]
#define OFF_HW_B   251904   // f16 frag [4][4nt][4kt][512]
#define OFF_RL_B   317440   // int rl[3][16][8]: e | (s<<16)
#define OFF_DYN_B  318976   // dynamic per-B buffers follow

__device__ __forceinline__ float ldf(const void* p, long i, int f32) {
    if (f32) return ((const float*)p)[i];
    unsigned int u = ((unsigned int)((const unsigned short*)p)[i]) << 16;
    return __uint_as_float(u);
}

__global__ void detect_kernel(const unsigned short* rs16, char* wsB) {
    __shared__ int bad;
    if (threadIdx.x == 0) bad = 0;
    __syncthreads();
    for (int i = threadIdx.x; i < 2048; i += 256) {
        unsigned int u = ((unsigned int)rs16[i]) << 16;
        float v = __uint_as_float(u);
        if (!(fabsf(v) < 1e6f)) atomicOr(&bad, 1);
    }
    __syncthreads();
    if (threadIdx.x == 0) *(int*)(wsB + OFF_FLAG_B) = bad ? 1 : 0;
}

__global__ void prep_kernel(const void* w1, const void* b1, const void* w2, const void* h0,
                            const void* hW, const void* gW, const void* Yw, const void* Xt,
                            char* wsB) {
    const int f32 = *(const int*)(wsB + OFF_FLAG_B);
    int i = blockIdx.x * 256 + threadIdx.x;
    _Float16* W1F = (_Float16*)(wsB + OFF_W1_B);
    _Float16* W2F = (_Float16*)(wsB + OFF_W2_B);
    _Float16* GWF = (_Float16*)(wsB + OFF_GW_B);
    _Float16* HWF = (_Float16*)(wsB + OFF_HW_B);
    float*    B1  = (float*)(wsB + OFF_B1_B);
    float*    XT  = (float*)(wsB + OFF_XT_B);
    _Float16* H0F = (_Float16*)(wsB + OFF_H0_B);
    _Float16* YWF = (_Float16*)(wsB + OFF_YW_B);

    if (i < 13824) {
        int lj = i / 1536, rem = i % 1536;
        int nt = rem >> 9, lane = (rem & 511) >> 3, e = rem & 7;
        int row = ((lane >> 4) << 3) + e;
        int col = (nt << 4) + (lane & 15);
        W1F[i] = (_Float16)((col < 45) ? ldf(w1, lj * 1440 + row * 45 + col, f32) : 0.f);
    }
    if (i < 36864) {
        int lj = i / 4096, rem = i & 4095;
        int nt = rem >> 10, kt = (rem >> 9) & 1, lane = (rem & 511) >> 3, e = rem & 7;
        int row = (kt << 5) + ((lane >> 4) << 3) + e;
        int col = (nt << 4) + (lane & 15);
        W2F[i] = (_Float16)((row < 45) ? ldf(w2, lj * 2880 + row * 64 + col, f32) : 0.f);
    }
    if (i < 73728) {
        int lj = i >> 13, rem = i & 8191;
        int nt = rem >> 10, kt = (rem >> 9) & 1, lane = (rem & 511) >> 3, e = rem & 7;
        int row = (kt << 5) + ((lane >> 4) << 3) + e;
        int col = (nt << 4) + (lane & 15);
        GWF[i] = (_Float16)ldf(gW, lj * 8192 + row * 128 + col, f32);
    }
    if (i < 32768) {
        int lj = i >> 13, rem = i & 8191;
        int nt = rem >> 11, kt = (rem >> 9) & 3, lane = (rem & 511) >> 3, e = rem & 7;
        int row = (kt << 5) + ((lane >> 4) << 3) + e;
        int col = (nt << 4) + (lane & 15);
        HWF[i] = (_Float16)ldf(hW, lj * 8192 + row * 64 + col, f32);
    }
    if (i < 432) { int lj = i / 48, n = i % 48; B1[i] = (n < 45) ? ldf(b1, lj * 45 + n, f32) : 0.f; }
    if (i < 128) XT[i] = ldf(Xt, i, f32);
    if (i < 128) H0F[i] = (_Float16)ldf(h0, i, f32);
    if (i < 256) YWF[i] = (_Float16)ldf(Yw, i, f32);
}

__global__ void rlbuild_kernel(const int* __restrict__ same_s, const int* __restrict__ same_r,
                               const int* __restrict__ anti_s, const int* __restrict__ anti_r,
                               const int* __restrict__ ne_s,   const int* __restrict__ ne_r,
                               char* wsB) {
    int lane = threadIdx.x;
    if (lane >= 48) return;
    int j = lane >> 4, r = lane & 15;
    int* rl = (int*)(wsB + OFF_RL_B) + lane * 8;
    int base = (j == 0) ? 0 : ((j == 1) ? 112 : 240);
    int cnt  = (j == 0) ? 112 : ((j == 1) ? 128 : 64);
    const int* rr = (j == 0) ? same_r : ((j == 1) ? anti_r : ne_r);
    const int* ss = (j == 0) ? same_s : ((j == 1) ? anti_s : ne_s);
    int n = 0;
    for (int i = 0; i < cnt && n < 8; ++i)
        if (rr[i] == r) { rl[n++] = (base + i) | (ss[i] << 16); }
    for (; n < 8; ++n) rl[n] = base;
}

// ====== weall body: one wave-task = (b, L, t); fused distance + feat + MLP ======
__device__ __forceinline__ void weall_body(
    int b, int L, int t, int lane,
    const void* __restrict__ rs, const void* __restrict__ coords,
    const int* __restrict__ same_s, const int* __restrict__ same_r,
    const int* __restrict__ anti_s, const int* __restrict__ anti_r,
    const int* __restrict__ ne_s,   const int* __restrict__ ne_r,
    const char* __restrict__ wsB, _Float16* __restrict__ hid,
    _Float16* __restrict__ weG, int f32)
{
    const int qd = lane >> 4, lm = lane & 15;
    const int j = (t < 7) ? 0 : ((t < 15) ? 1 : 2);
    const int lj = L * 3 + j;
    const int tj0 = (j == 0) ? 0 : ((j == 1) ? 7 : 15);
    const int le = (t - tj0) * 16 + lm;

    int s, r;
    if (j == 0)      { s = same_s[le]; r = same_r[le]; }
    else if (j == 1) { s = anti_s[le]; r = anti_r[le]; }
    else             { s = ne_s[le];   r = ne_r[le]; }
    long rb = ((long)b * NE + r) * 3;
    float bx = ldf(rs, rb + 0, f32), by = ldf(rs, rb + 1, f32), bz = ldf(rs, rb + 2, f32);
    float ax, ay, az;
    if (j < 2) {
        long sb = ((long)b * NE + s) * 3;
        ax = ldf(rs, sb + 0, f32); ay = ldf(rs, sb + 1, f32); az = ldf(rs, sb + 2, f32);
    } else {
        ax = ldf(coords, s * 3 + 0, f32); ay = ldf(coords, s * 3 + 1, f32); az = ldf(coords, s * 3 + 2, f32);
    }
    float dx = ax - bx, dy = ay - by, dz = az - bz;
    float d = sqrtf(dx * dx + dy * dy + dz * dz);

    const half8* W1F_lj = (const half8*)(wsB + OFF_W1_B) + lj * 192;
    half8 w0 = W1F_lj[lane], w1v = W1F_lj[64 + lane], w2v = W1F_lj[128 + lane];
    const float* B1 = (const float*)(wsB + OFF_B1_B);
    float bi0 = B1[lj * 48 + lm], bi1 = B1[lj * 48 + 16 + lm], bi2 = B1[lj * 48 + 32 + lm];

    {
        half8 z8 = {0,0,0,0,0,0,0,0};
        *(half8*)(hid + lane * 8) = z8;
        *(half8*)(hid + 512 + lane * 8) = z8;
    }

    float d2 = d * d;
    half8 fa;
    #pragma unroll
    for (int ii = 0; ii < 8; ++ii) {
        float qf = (float)(qd * 8 + ii) * (1.f / 31.f);
        float mu = 10.f * qf * qf;
        float isg = 7.f * __builtin_amdgcn_rcpf(1.f + 10.f * qf);
        float tt = (d - mu) * isg;
        fa[ii] = (_Float16)(d2 * __expf(-(d + tt * tt)));
    }

    floatx4 c0 = {0.f,0.f,0.f,0.f}, c1 = c0, c2 = c0;
    c0 = __builtin_amdgcn_mfma_f32_16x16x32_f16(fa, w0,  c0, 0, 0, 0);
    c1 = __builtin_amdgcn_mfma_f32_16x16x32_f16(fa, w1v, c1, 0, 0, 0);
    c2 = __builtin_amdgcn_mfma_f32_16x16x32_f16(fa, w2v, c2, 0, 0, 0);
    #pragma unroll
    for (int rr = 0; rr < 4; ++rr) {
        int row = qd * 4 + rr;
        float v0 = c0[rr] + bi0, v1 = c1[rr] + bi1, v2 = c2[rr] + bi2;
        v0 = v0 * __builtin_amdgcn_rcpf(1.f + __expf(-v0));
        v1 = v1 * __builtin_amdgcn_rcpf(1.f + __expf(-v1));
        v2 = v2 * __builtin_amdgcn_rcpf(1.f + __expf(-v2));
        hid[row * 64 + lm]      = (_Float16)v0;
        hid[row * 64 + 16 + lm] = (_Float16)v1;
        hid[row * 64 + 32 + lm] = (_Float16)v2;
    }
    half8 a0 = *(const half8*)(hid + lm * 64 + qd * 8);
    half8 a1 = *(const half8*)(hid + lm * 64 + 32 + qd * 8);

    const half8* W2F_lj = (const half8*)(wsB + OFF_W2_B) + lj * 512;
    _Float16* wrow = weG + ((size_t)(b * 3 + L) * 304 + (size_t)(t * 16)) * 64;
    #pragma unroll
    for (int nt = 0; nt < 4; ++nt) {
        half8 bk0 = W2F_lj[nt * 128 + lane], bk1 = W2F_lj[nt * 128 + 64 + lane];
        floatx4 acc = {0.f,0.f,0.f,0.f};
        acc = __builtin_amdgcn_mfma_f32_16x16x32_f16(a0, bk0, acc, 0, 0, 0);
        acc = __builtin_amdgcn_mfma_f32_16x16x32_f16(a1, bk1, acc, 0, 0, 0);
        const int k = nt * 16 + lm;
        #pragma unroll
        for (int rr = 0; rr < 4; ++rr)
            wrow[(size_t)(qd * 4 + rr) * 64 + k] = (_Float16)acc[rr];
    }
}

// ====== tailhx body (r10-proven) ======
template<int L, bool LAST>
__device__ __forceinline__ void tailhx_body(
    int b, const char* __restrict__ wsB, const _Float16* __restrict__ weG,
    float* __restrict__ elecC, _Float16* __restrict__ hxG, void* __restrict__ out)
{
    const int tid = threadIdx.x;
    const int q = tid >> 6, lane = tid & 63;
    const int qd = lane >> 4, lm = lane & 15;
    const int f32 = *(const int*)(wsB + OFF_FLAG_B);

    __shared__ float zS[3 * 16 * 68];
    __shared__ _Float16 hxS[2 * 1024];
    __shared__ _Float16 nucS[256];
    __shared__ int rlS[384];
    __shared__ __align__(16) _Float16 elecB[16 * 136];

    const half8* GWF = (const half8*)(wsB + OFF_GW_B);
    const half8* HWF = (const half8*)(wsB + OFF_HW_B);
    const float* XT  = (const float*)(wsB + OFF_XT_B);
    const _Float16* H0F = (const _Float16*)(wsB + OFF_H0_B);
    const _Float16* YWF = (const _Float16*)(wsB + OFF_YW_B);

    for (int i = tid; i < 384; i += 256) rlS[i] = ((const int*)(wsB + OFF_RL_B))[i];
    if (L == 0) {
        for (int i = tid; i < 2048; i += 256) hxS[i] = H0F[((i >> 10) << 6) + (i & 63)];
    } else {
        int i = tid * 8;
        *(half8*)(hxS + i) = *(const half8*)(hxG + (size_t)b * 2048 + i);
    }
    if (tid < 256) nucS[tid] = YWF[tid];
    __syncthreads();

    const _Float16* web = weG + (size_t)(b * 3 + L) * 304 * 64;
    #pragma unroll
    for (int rr4 = 0; rr4 < 4; ++rr4) {
        const int r = q * 4 + rr4;
        #pragma unroll
        for (int j = 0; j < 3; ++j) {
            const int cnt = (j == 0) ? 7 : ((j == 1) ? 8 : 4);
            const int* rlj = rlS + (j * 16 + r) * 8;
            float acc = 0.f;
            #pragma unroll
            for (int i = 0; i < 8; ++i) {
                if (i < cnt) {
                    int pk = rlj[i];
                    int e = pk & 0xFFFF, s = pk >> 16;
                    float wev = (float)web[(size_t)e * 64 + lane];
                    float hxv = (j == 2) ? (float)nucS[s * 64 + lane]
                                         : (float)hxS[j * 1024 + s * 64 + lane];
                    acc += wev * hxv;
                }
            }
            zS[j * 1088 + r * 68 + lane] = acc;
        }
    }
    __syncthreads();

    half8 zf[6];
    #pragma unroll
    for (int jj = 0; jj < 6; ++jj) {
        int j = jj >> 1, kh = jj & 1;
        const float* zr = zS + j * 1088 + lm * 68 + kh * 32 + qd * 8;
        floatx4 va = *(const floatx4*)zr;
        floatx4 vb = *(const floatx4*)(zr + 4);
        #pragma unroll
        for (int ii = 0; ii < 4; ++ii) { zf[jj][ii] = (_Float16)va[ii]; zf[jj][4 + ii] = (_Float16)vb[ii]; }
    }
    #pragma unroll
    for (int u = 0; u < 2; ++u) {
        int t2 = q * 2 + u;
        floatx4 acc;
        if (L == 0) {
            float xv = XT[t2 * 16 + lm];
            acc[0] = xv; acc[1] = xv; acc[2] = xv; acc[3] = xv;
        } else {
            acc = *(const floatx4*)(elecC + (size_t)b * 2048 + (size_t)((qd * 8 + t2) * 16 + lm) * 4);
        }
        #pragma unroll
        for (int jj = 0; jj < 6; ++jj) {
            int j = jj >> 1, kh = jj & 1;
            half8 g = GWF[(L * 3 + j) * 1024 + t2 * 128 + kh * 64 + lane];
            acc = __builtin_amdgcn_mfma_f32_16x16x32_f16(zf[jj], g, acc, 0, 0, 0);
        }
        if (LAST) {
            if (f32) {
                float* o = (float*)out + (size_t)b * 2048;
                #pragma unroll
                for (int r = 0; r < 4; ++r) o[(qd * 4 + r) * 128 + t2 * 16 + lm] = acc[r];
            } else {
                __hip_bfloat16* o = (__hip_bfloat16*)out + (size_t)b * 2048;
                #pragma unroll
                for (int r = 0; r < 4; ++r) o[(qd * 4 + r) * 128 + t2 * 16 + lm] = __float2bfloat16(acc[r]);
            }
        } else {
            *(floatx4*)(elecC + (size_t)b * 2048 + (size_t)((qd * 8 + t2) * 16 + lm) * 4) = acc;
            #pragma unroll
            for (int r = 0; r < 4; ++r)
                elecB[(qd * 4 + r) * 136 + t2 * 16 + lm] = (_Float16)acc[r];
        }
    }
    if (!LAST) {
        __syncthreads();
        half8 ae[4];
        #pragma unroll
        for (int kt = 0; kt < 4; ++kt)
            ae[kt] = *(const half8*)(elecB + lm * 136 + kt * 32 + qd * 8);
        #pragma unroll
        for (int u = 0; u < 2; ++u) {
            int idx = q * 2 + u;
            int j = idx >> 2, nt = idx & 3;
            floatx4 acc = {0.f,0.f,0.f,0.f};
            #pragma unroll
            for (int kt = 0; kt < 4; ++kt) {
                half8 g = HWF[(size_t)(((L * 2 + j) * 4 + nt) * 4 + kt) * 64 + lane];
                acc = __builtin_amdgcn_mfma_f32_16x16x32_f16(ae[kt], g, acc, 0, 0, 0);
            }
            #pragma unroll
            for (int r = 0; r < 4; ++r)
                hxG[(size_t)b * 2048 + j * 1024 + (qd * 4 + r) * 64 + nt * 16 + lm] = (_Float16)acc[r];
        }
    }
}

__global__ __launch_bounds__(256, 4)
void weall0_kernel(const void* __restrict__ rs, const void* __restrict__ coords,
                   const int* __restrict__ same_s, const int* __restrict__ same_r,
                   const int* __restrict__ anti_s, const int* __restrict__ anti_r,
                   const int* __restrict__ ne_s,   const int* __restrict__ ne_r,
                   const char* __restrict__ wsB, _Float16* __restrict__ weG, int ntask) {
    __shared__ __align__(16) _Float16 hidA[4][1024];
    const int wv = threadIdx.x >> 6, lane = threadIdx.x & 63;
    int task = blockIdx.x * 4 + wv;
    if (task >= ntask) return;
    int b = task / 19, t = task - b * 19;
    const int f32 = *(const int*)(wsB + OFF_FLAG_B);
    weall_body(b, 0, t, lane, rs, coords, same_s, same_r, anti_s, anti_r, ne_s, ne_r,
               wsB, hidA[wv], weG, f32);
}

__global__ __launch_bounds__(256, 4)
void combo_kernel(const void* __restrict__ rs, const void* __restrict__ coords,
                  const int* __restrict__ same_s, const int* __restrict__ same_r,
                  const int* __restrict__ anti_s, const int* __restrict__ anti_r,
                  const int* __restrict__ ne_s,   const int* __restrict__ ne_r,
                  const char* __restrict__ wsB, _Float16* __restrict__ weG,
                  float* __restrict__ elecC, _Float16* __restrict__ hxG,
                  void* __restrict__ out, int Bn) {
    __shared__ __align__(16) _Float16 hidA[4][1024];
    if ((int)blockIdx.x < Bn) {
        tailhx_body<0, false>(blockIdx.x, wsB, weG, elecC, hxG, out);
    } else {
        const int wv = threadIdx.x >> 6, lane = threadIdx.x & 63;
        int task = ((int)blockIdx.x - Bn) * 4 + wv;
        if (task < Bn * 38) {
            int b = task / 38, lt = task - b * 38;
            int L = 1 + lt / 19, t = lt - (L - 1) * 19;
            const int f32 = *(const int*)(wsB + OFF_FLAG_B);
            weall_body(b, L, t, lane, rs, coords, same_s, same_r, anti_s, anti_r, ne_s, ne_r,
                       wsB, hidA[wv], weG, f32);
        }
    }
}

template<int L, bool LAST>
__global__ __launch_bounds__(256, 4)
void tailhx_kernel(const char* __restrict__ wsB, const _Float16* __restrict__ weG,
                   float* __restrict__ elecC, _Float16* __restrict__ hxG,
                   void* __restrict__ out) {
    tailhx_body<L, LAST>(blockIdx.x, wsB, weG, elecC, hxG, out);
}

// ================= FALLBACK: round-4 fused kernel (used if ws too small) ==========
__device__ __forceinline__ half8 mkfeat(float d, int qd) {
    float env = d * d * __expf(-d);
    half8 a;
    #pragma unroll
    for (int ii = 0; ii < 8; ++ii) {
        float qf = (float)(qd * 8 + ii) * (1.f / 31.f);
        float mu = 10.f * qf * qf;
        float isg = 7.f * __builtin_amdgcn_rcpf(1.f + 10.f * qf);
        float tt = (d - mu) * isg;
        a[ii] = (_Float16)(env * __expf(-tt * tt));
    }
    return a;
}

template<int MT>
__device__ __forceinline__ void edge_class(
    const half8 (&fa)[MT], int ebase,
    const _Float16* __restrict__ hxsel,
    const unsigned char* __restrict__ esS, const unsigned char* __restrict__ erS,
    _Float16* __restrict__ hid0, _Float16* __restrict__ hid1,
    float* __restrict__ zbuf,
    const half8* __restrict__ W1F_lj, const float* __restrict__ B1_lj,
    const half8* __restrict__ W2F_lj,
    int lane, int qd, int lm)
{
    half8 w0 = W1F_lj[lane], w1v = W1F_lj[64 + lane], w2v = W1F_lj[128 + lane];
    float bi0 = B1_lj[lm], bi1 = B1_lj[16 + lm], bi2 = B1_lj[32 + lm];
    half8 bk[4][2];
    #pragma unroll
    for (int nt = 0; nt < 4; ++nt) {
        bk[nt][0] = W2F_lj[nt * 128 + lane];
        bk[nt][1] = W2F_lj[nt * 128 + 64 + lane];
    }
    #pragma unroll
    for (int mt = 0; mt < MT; ++mt) {
        _Float16* hidb = (mt & 1) ? hid1 : hid0;
        floatx4 c0 = {0,0,0,0}, c1 = c0, c2 = c0;
        c0 = __builtin_amdgcn_mfma_f32_16x16x32_f16(fa[mt], w0,  c0, 0, 0, 0);
        c1 = __builtin_amdgcn_mfma_f32_16x16x32_f16(fa[mt], w1v, c1, 0, 0, 0);
        c2 = __builtin_amdgcn_mfma_f32_16x16x32_f16(fa[mt], w2v, c2, 0, 0, 0);
        #pragma unroll
        for (int r = 0; r < 4; ++r) {
            int row = qd * 4 + r;
            float v0 = c0[r] + bi0, v1 = c1[r] + bi1, v2 = c2[r] + bi2;
            v0 = v0 * __builtin_amdgcn_rcpf(1.f + __expf(-v0));
            v1 = v1 * __builtin_amdgcn_rcpf(1.f + __expf(-v1));
            v2 = v2 * __builtin_amdgcn_rcpf(1.f + __expf(-v2));
            hidb[row * 72 + lm]      = (_Float16)v0;
            hidb[row * 72 + 16 + lm] = (_Float16)v1;
            hidb[row * 72 + 32 + lm] = (_Float16)v2;
        }
        half8 a0 = *(const half8*)(hidb + lm * 72 + qd * 8);
        half8 a1 = *(const half8*)(hidb + lm * 72 + 32 + qd * 8);
        #pragma unroll
        for (int nt = 0; nt < 4; ++nt) {
            floatx4 acc = {0,0,0,0};
            acc = __builtin_amdgcn_mfma_f32_16x16x32_f16(a0, bk[nt][0], acc, 0, 0, 0);
            acc = __builtin_amdgcn_mfma_f32_16x16x32_f16(a1, bk[nt][1], acc, 0, 0, 0);
            #pragma unroll
            for (int r = 0; r < 4; ++r) {
                int e = ebase + mt * 16 + qd * 4 + r;
                int s = esS[e], rr = erS[e];
                float weh = acc[r] * (float)hxsel[s * 68 + nt * 16 + lm];
                atomicAdd(&zbuf[rr * 68 + nt * 16 + lm], weh);
            }
        }
    }
}

__global__ __launch_bounds__(256, 2)
void schnet_kernel(const void* __restrict__ rs,
                   const void* __restrict__ coords,
                   const int* __restrict__ same_s, const int* __restrict__ same_r,
                   const int* __restrict__ anti_s, const int* __restrict__ anti_r,
                   const int* __restrict__ ne_s,   const int* __restrict__ ne_r,
                   const char* __restrict__ wsB,
                   void* __restrict__ out, int Bn) {
    const int tid = threadIdx.x;
    const int wv = tid >> 6, lane = tid & 63;
    const int qd = lane >> 4, lm = lane & 15;
    const int f32 = *(const int*)(wsB + OFF_FLAG_B);

    __shared__ float dLA[4][304];
    __shared__ float zbufA[4][16 * 68];
    __shared__ _Float16 hxA[4][2 * 16 * 68];
    __shared__ _Float16 scrA[4][2304];
    __shared__ _Float16 nucS[4 * 68];
    __shared__ unsigned char esS[E_TOT], erS[E_TOT];

    const float*    B1  = (const float*)(wsB + OFF_B1_B);
    const float*    XT  = (const float*)(wsB + OFF_XT_B);
    const _Float16* H0F = (const _Float16*)(wsB + OFF_H0_B);
    const _Float16* YWF = (const _Float16*)(wsB + OFF_YW_B);
    const half8*    W1F = (const half8*)(wsB + OFF_W1_B);
    const half8*    W2F = (const half8*)(wsB + OFF_W2_B);
    const half8*    GWF = (const half8*)(wsB + OFF_GW_B);
    const half8*    HWF = (const half8*)(wsB + OFF_HW_B);

    for (int i = tid; i < E_TOT; i += 256) {
        int s, r;
        if (i < 112)      { s = same_s[i];       r = same_r[i]; }
        else if (i < 240) { s = anti_s[i - 112]; r = anti_r[i - 112]; }
        else              { s = ne_s[i - 240];   r = ne_r[i - 240]; }
        esS[i] = (unsigned char)s; erS[i] = (unsigned char)r;
    }
    for (int i = tid; i < NN * KD; i += 256)
        nucS[(i >> 6) * 68 + (i & 63)] = YWF[i];
    for (int i = tid; i < 4 * 2304; i += 256) ((_Float16*)scrA)[i] = (_Float16)0.f;
    __syncthreads();

    int b = blockIdx.x * 4 + wv;
    if (b >= Bn) b = Bn - 1;

    float*     dLw   = dLA[wv];
    float*     zbuf  = zbufA[wv];
    _Float16*  hxB   = hxA[wv];
    _Float16*  elecB = scrA[wv];
    _Float16*  hid0  = scrA[wv];
    _Float16*  hid1  = scrA[wv] + 1152;

    for (int e = lane; e < E_TOT; e += 64) {
        int s = esS[e], r = erS[e];
        long rb = ((long)b * NE + r) * 3;
        float bx = ldf(rs, rb + 0, f32), by = ldf(rs, rb + 1, f32), bz = ldf(rs, rb + 2, f32);
        float ax, ay, az;
        if (e < 240) {
            long sb = ((long)b * NE + s) * 3;
            ax = ldf(rs, sb + 0, f32); ay = ldf(rs, sb + 1, f32); az = ldf(rs, sb + 2, f32);
        } else {
            ax = ldf(coords, s * 3 + 0, f32); ay = ldf(coords, s * 3 + 1, f32); az = ldf(coords, s * 3 + 2, f32);
        }
        float dx = ax - bx, dy = ay - by, dz = az - bz;
        dLw[e] = sqrtf(dx * dx + dy * dy + dz * dz);
    }

    half8 faS[7], faA[8], faN[4];
    #pragma unroll
    for (int mt = 0; mt < 7; ++mt) faS[mt] = mkfeat(dLw[mt * 16 + lm], qd);
    #pragma unroll
    for (int mt = 0; mt < 8; ++mt) faA[mt] = mkfeat(dLw[112 + mt * 16 + lm], qd);
    #pragma unroll
    for (int mt = 0; mt < 4; ++mt) faN[mt] = mkfeat(dLw[240 + mt * 16 + lm], qd);

    floatx4 eacc[8];
    #pragma unroll
    for (int t = 0; t < 8; ++t) {
        float xv = XT[t * 16 + lm];
        eacc[t][0] = xv; eacc[t][1] = xv; eacc[t][2] = xv; eacc[t][3] = xv;
    }

    for (int i = lane; i < 2 * NE * KD; i += 64) {
        int j = i >> 10, s = (i >> 6) & 15, k = i & 63;
        hxB[j * 1088 + s * 68 + k] = H0F[j * 64 + k];
    }

    for (int l = 0; l < 3; ++l) {
        if (l > 0) {
            #pragma unroll
            for (int t = 0; t < 8; ++t)
                #pragma unroll
                for (int r = 0; r < 4; ++r)
                    elecB[(qd * 4 + r) * 136 + t * 16 + lm] = (_Float16)eacc[t][r];
            half8 ae[4];
            #pragma unroll
            for (int kt = 0; kt < 4; ++kt)
                ae[kt] = *(const half8*)(elecB + lm * 136 + kt * 32 + qd * 8);
            #pragma unroll
            for (int j = 0; j < 2; ++j) {
                int lj4 = (l - 1) * 2 + j;
                #pragma unroll
                for (int nt = 0; nt < 4; ++nt) {
                    const half8* Bb = HWF + (lj4 * 4 + nt) * 4 * 64;
                    floatx4 acc = {0,0,0,0};
                    #pragma unroll
                    for (int kt = 0; kt < 4; ++kt)
                        acc = __builtin_amdgcn_mfma_f32_16x16x32_f16(ae[kt], Bb[kt * 64 + lane], acc, 0, 0, 0);
                    #pragma unroll
                    for (int r = 0; r < 4; ++r)
                        hxB[j * 1088 + (qd * 4 + r) * 68 + nt * 16 + lm] = (_Float16)acc[r];
                }
            }
        }

        #pragma unroll
        for (int j = 0; j < 3; ++j) {
            const int lj = l * 3 + j;
            for (int i = lane; i < 16 * 68; i += 64) zbuf[i] = 0.f;

            const half8* W1F_lj = W1F + lj * 192;
            const float* B1_lj  = B1 + lj * 48;
            const half8* W2F_lj = W2F + lj * 512;
            if (j == 0)
                edge_class<7>(faS, 0,   hxB,        esS, erS, hid0, hid1, zbuf, W1F_lj, B1_lj, W2F_lj, lane, qd, lm);
            else if (j == 1)
                edge_class<8>(faA, 112, hxB + 1088, esS, erS, hid0, hid1, zbuf, W1F_lj, B1_lj, W2F_lj, lane, qd, lm);
            else
                edge_class<4>(faN, 240, nucS,       esS, erS, hid0, hid1, zbuf, W1F_lj, B1_lj, W2F_lj, lane, qd, lm);

            floatx4 za0a = *(const floatx4*)(zbuf + lm * 68 + qd * 8);
            floatx4 za0b = *(const floatx4*)(zbuf + lm * 68 + qd * 8 + 4);
            floatx4 za1a = *(const floatx4*)(zbuf + lm * 68 + 32 + qd * 8);
            floatx4 za1b = *(const floatx4*)(zbuf + lm * 68 + 32 + qd * 8 + 4);
            half8 A0, A1;
            #pragma unroll
            for (int ii = 0; ii < 4; ++ii) {
                A0[ii] = (_Float16)za0a[ii]; A0[4 + ii] = (_Float16)za0b[ii];
                A1[ii] = (_Float16)za1a[ii]; A1[4 + ii] = (_Float16)za1b[ii];
            }
            const half8* GWF_lj = GWF + lj * 1024;
            #pragma unroll
            for (int t = 0; t < 8; ++t) {
                half8 g0 = GWF_lj[t * 128 + lane];
                half8 g1 = GWF_lj[t * 128 + 64 + lane];
                eacc[t] = __builtin_amdgcn_mfma_f32_16x16x32_f16(A0, g0, eacc[t], 0, 0, 0);
                eacc[t] = __builtin_amdgcn_mfma_f32_16x16x32_f16(A1, g1, eacc[t], 0, 0, 0);
            }
        }
    }

    if (f32) {
        float* o = (float*)out + (long)b * (NE * DDIM);
        #pragma unroll
        for (int t = 0; t < 8; ++t)
            #pragma unroll
            for (int r = 0; r < 4; ++r)
                o[(qd * 4 + r) * 128 + t * 16 + lm] = eacc[t][r];
    } else {
        __hip_bfloat16* o = (__hip_bfloat16*)out + (long)b * (NE * DDIM);
        #pragma unroll
        for (int t = 0; t < 8; ++t)
            #pragma unroll
            for (int r = 0; r < 4; ++r)
                o[(qd * 4 + r) * 128 + t * 16 + lm] = __float2bfloat16(eacc[t][r]);
    }
}

extern "C" void kernel_launch(void* const* d_in, const int* in_sizes, int n_in,
                              void* d_out, int out_size, void* d_ws, size_t ws_size,
                              hipStream_t stream) {
    const void* rs     = d_in[0];
    const void* coords = d_in[1];
    const void* X_tab  = d_in[2];
    const void* Y_w    = d_in[3];
    const void* wW1    = d_in[4];
    const void* wb1    = d_in[5];
    const void* wW2    = d_in[6];
    const void* h0     = d_in[7];
    const void* hW     = d_in[8];
    const void* gW     = d_in[9];
    const int* same_s = (const int*)d_in[10];
    const int* same_r = (const int*)d_in[11];
    const int* anti_s = (const int*)d_in[12];
    const int* anti_r = (const int*)d_in[13];
    const int* ne_s   = (const int*)d_in[14];
    const int* ne_r   = (const int*)d_in[15];
    char* wsB = (char*)d_ws;

    const int Bn = in_sizes[0] / (NE * 3);

    detect_kernel<<<1, 256, 0, stream>>>((const unsigned short*)rs, wsB);
    prep_kernel<<<288, 256, 0, stream>>>(wW1, wb1, wW2, h0, hW, gW, Y_w, X_tab, wsB);

    size_t offWe    = OFF_DYN_B;                          // f16 [Bn][3][304][64]
    size_t offElecC = offWe    + (size_t)Bn * 116736;     // f32 [Bn][2048]
    size_t offHxG   = offElecC + (size_t)Bn * 8192;       // f16 [Bn][2][16][64]
    size_t need     = offHxG   + (size_t)Bn * 4096;

    if (ws_size >= need) {
        _Float16* weG   = (_Float16*)(wsB + offWe);
        float*    elecC = (float*)(wsB + offElecC);
        _Float16* hxG   = (_Float16*)(wsB + offHxG);

        rlbuild_kernel<<<1, 64, 0, stream>>>(same_s, same_r, anti_s, anti_r, ne_s, ne_r, wsB);

        const int n0 = Bn * 19;
        weall0_kernel<<<(n0 + 3) / 4, 256, 0, stream>>>(rs, coords, same_s, same_r,
                                                        anti_s, anti_r, ne_s, ne_r, wsB, weG, n0);

        const int gD = Bn + (Bn * 38 + 3) / 4;
        combo_kernel<<<gD, 256, 0, stream>>>(rs, coords, same_s, same_r, anti_s, anti_r,
                                             ne_s, ne_r, wsB, weG, elecC, hxG, d_out, Bn);

        tailhx_kernel<1, false><<<Bn, 256, 0, stream>>>(wsB, weG, elecC, hxG, d_out);
        tailhx_kernel<2, true><<<Bn, 256, 0, stream>>>(wsB, weG, elecC, hxG, d_out);
    } else {
        schnet_kernel<<<(Bn + 3) / 4, 256, 0, stream>>>(rs, coords, same_s, same_r, anti_s, anti_r,
                                                        ne_s, ne_r, wsB, d_out, Bn);
    }
}